// Round 1
// baseline (630.665 us; speedup 1.0000x reference)
//
#include <hip/hip_runtime.h>
#include <math.h>

// Problem constants
#define BB 4
#define NN 512
#define HH 64
#define NHH 4
#define HDD 16
#define LL 3
#define NNSQ 262144          // N*N
#define FFF 256

// ---------------- wave helpers ----------------
__device__ __forceinline__ float wsum(float x) {
#pragma unroll
    for (int o = 1; o < 64; o <<= 1) x += __shfl_xor(x, o);
    return x;
}
__device__ __forceinline__ float wmaxr(float x) {
#pragma unroll
    for (int o = 1; o < 64; o <<= 1) x = fmaxf(x, __shfl_xor(x, o));
    return x;
}

// ---------------- adjacency bitsets ----------------
// grid 4096 x 256 : wave per (row, 64-col chunk)
__global__ void k_adj(const int* __restrict__ em, unsigned long long* __restrict__ adj) {
    int wid = blockIdx.x * 4 + (threadIdx.x >> 6);
    int lane = threadIdx.x & 63;
    int chunk = wid & 7;
    int row = wid >> 3;                 // b*N + i
    int j = chunk * 64 + lane;
    int v = em[(size_t)row * NN + j];
    unsigned long long bal = __ballot(v != 0);
    if (lane == 0) adj[row * 8 + chunk] = bal;
}

// ---------------- spd bias lookup table [l][v][h], v in 0..10 ----------------
__global__ void k_spd_table(const float* __restrict__ s1w, const float* __restrict__ s1b,
                            const float* __restrict__ s2w, const float* __restrict__ s2b,
                            float* __restrict__ table) {
    int t = threadIdx.x;
    if (t >= 132) return;
    int l = t / 44; int r = t % 44; int v = r / 4; int hh = r % 4;
    float x = (float)v * 0.1f;
    float acc = s2b[l * 4 + hh];
#pragma unroll
    for (int c = 0; c < 16; c++) {
        float tt = x * s1w[l * 16 + c] + s1b[l * 16 + c];
        tt = tt >= 0.f ? tt : 0.2f * tt;
        acc += tt * s2w[(l * 16 + c) * 4 + hh];
    }
    table[t] = acc;
}

// ---------------- BFS (levels 1..9, >=10 -> 10) ----------------
// grid 2048 x 64 : one wave per source row
__global__ void k_bfs(const unsigned long long* __restrict__ adj, unsigned char* __restrict__ spd) {
    __shared__ unsigned long long vis[8], fro[8], nxt[8];
    __shared__ unsigned long long dist8[64];
    unsigned char* dist = (unsigned char*)dist8;
    int t = threadIdx.x;
    int row = blockIdx.x;               // b*N + i
    int b = row >> 9; int src = row & 511;
    dist8[t] = 0x0A0A0A0A0A0A0A0AULL;   // init all to 10
    if (t < 8) { vis[t] = 0ULL; fro[t] = 0ULL; }
    __syncthreads();
    if (t == 0) {
        dist[src] = 0;
        vis[src >> 6] = 1ULL << (src & 63);
        fro[src >> 6] = 1ULL << (src & 63);
    }
    __syncthreads();
    const unsigned long long* arow = adj + (size_t)b * NN * 8;
    for (int d = 1; d <= 9; d++) {
        if (t < 8) nxt[t] = 0ULL;
        __syncthreads();
        int c = t >> 3, w = t & 7;
        unsigned long long f = fro[c];
        unsigned long long acc = 0ULL;
        while (f) {
            int k = (c << 6) + __builtin_ctzll(f);
            f &= f - 1;
            acc |= arow[k * 8 + w];
        }
        if (acc) atomicOr(&nxt[w], acc);
        __syncthreads();
        if (t < 8) {
            unsigned long long nw = nxt[t] & ~vis[t];
            vis[t] |= nw;
            fro[t] = nw;
            while (nw) {
                int j = (t << 6) + __builtin_ctzll(nw);
                nw &= nw - 1;
                dist[j] = (unsigned char)d;
            }
        }
        __syncthreads();
    }
    ((unsigned long long*)(spd + (size_t)row * NN))[t] = dist8[t];
}

// ---------------- fill bias tensor with spd-bias ----------------
// grid 4096 x 256 : thread per (b,i,j)
__global__ void k_fill_bias(const unsigned char* __restrict__ spd, const float* __restrict__ table,
                            float* __restrict__ bias) {
    __shared__ float tab[132];
    int t = threadIdx.x;
    if (t < 132) tab[t] = table[t];
    __syncthreads();
    int idx = blockIdx.x * 256 + t;     // (b*N+i)*N + j
    int v = spd[idx];
    int b = idx >> 18; int ij = idx & (NNSQ - 1);
#pragma unroll
    for (int l = 0; l < 3; l++)
#pragma unroll
        for (int hh = 0; hh < 4; hh++)
            bias[(size_t)((l * 4 + b) * 4 + hh) * NNSQ + ij] = tab[(l * 11 + v) * 4 + hh];
}

// ---------------- compact edge list ----------------
__global__ void k_compact(const int* __restrict__ em, unsigned int* __restrict__ counter,
                          unsigned int* __restrict__ elist) {
    int idx = blockIdx.x * 256 + threadIdx.x;
    int lane = threadIdx.x & 63;
    bool m = em[idx] != 0;
    unsigned long long bal = __ballot(m);
    int cnt = __popcll(bal);
    unsigned int base = 0;
    if (lane == 0 && cnt) base = atomicAdd(counter, (unsigned int)cnt);
    base = (unsigned int)__shfl((int)base, 0);
    if (m) {
        int pre = __popcll(bal & ((1ULL << lane) - 1ULL));
        elist[base + pre] = (unsigned int)idx;
    }
}

// ---------------- edge bias MLP at true edges ----------------
// grid (4096, 3) x 256 : thread per (edge, layer)
__global__ __launch_bounds__(256) void k_edge_bias(
    const float* __restrict__ ef, const unsigned int* __restrict__ counter,
    const unsigned int* __restrict__ elist,
    const float* __restrict__ epw, const float* __restrict__ epb,
    const float* __restrict__ eb1w, const float* __restrict__ eb1b,
    const float* __restrict__ lng, const float* __restrict__ lnb,
    const float* __restrict__ eb2w, const float* __restrict__ eb2b,
    float* __restrict__ bias) {
    unsigned int count = *counter;
    unsigned int idx = blockIdx.x * 256 + threadIdx.x;
    if (idx >= count) return;
    int l = blockIdx.y;
    unsigned int pos = elist[idx];      // b*N*N + i*N + j
    int b = pos >> 18; int ij = pos & (NNSQ - 1);
    const float* e7 = ef + (size_t)pos * 7;
    float f0 = e7[0], f1 = e7[1], f2 = e7[2], f3 = e7[3], f4 = e7[4], f5 = e7[5], f6 = e7[6];
    float tt[16];
#pragma unroll
    for (int c = 0; c < 16; c++) tt[c] = eb1b[l * 16 + c];
    const float* W1 = eb1w + l * 1024;
    for (int k = 0; k < 64; k++) {
        float ek = epb[k] + f0 * epw[k] + f1 * epw[64 + k] + f2 * epw[128 + k] + f3 * epw[192 + k]
                 + f4 * epw[256 + k] + f5 * epw[320 + k] + f6 * epw[384 + k];
#pragma unroll
        for (int c = 0; c < 16; c++) tt[c] += ek * W1[k * 16 + c];
    }
    float m = 0.f;
#pragma unroll
    for (int c = 0; c < 16; c++) m += tt[c];
    m *= 0.0625f;
    float var = 0.f;
#pragma unroll
    for (int c = 0; c < 16; c++) { float d = tt[c] - m; var += d * d; }
    var *= 0.0625f;
    float inv = rsqrtf(var + 1e-5f);
#pragma unroll
    for (int c = 0; c < 16; c++) {
        float x = (tt[c] - m) * inv * lng[l * 16 + c] + lnb[l * 16 + c];
        tt[c] = x >= 0.f ? x : 0.2f * x;
    }
#pragma unroll
    for (int hh = 0; hh < 4; hh++) {
        float a = eb2b[l * 4 + hh];
#pragma unroll
        for (int c = 0; c < 16; c++) a += tt[c] * eb2w[(l * 16 + c) * 4 + hh];
        bias[(size_t)((l * 4 + b) * 4 + hh) * NNSQ + ij] = a;
    }
}

// ---------------- node projection ----------------
// grid 512 x 256 : wave per row
__global__ void k_node_proj(const float* __restrict__ nf, const float* __restrict__ w,
                            const float* __restrict__ bb, float* __restrict__ h) {
    int wid = blockIdx.x * 4 + (threadIdx.x >> 6);
    int f = threadIdx.x & 63;
    const float* r = nf + (size_t)wid * 18;
    float acc = bb[f];
#pragma unroll
    for (int c = 0; c < 18; c++) acc += r[c] * w[c * 64 + f];
    h[(size_t)wid * 64 + f] = acc;
}

// ---------------- QKV projection (no bias in reference) ----------------
// grid 128 x 256 : block handles 16 rows, wave handles 4 rows
__global__ __launch_bounds__(256) void k_qkv(
    const float* __restrict__ h,
    const float* __restrict__ WQ, const float* __restrict__ WK, const float* __restrict__ WV,
    float* __restrict__ Q, float* __restrict__ K, float* __restrict__ V) {
    __shared__ float h_lds[16][64];
    int t = threadIdx.x;
    size_t base = (size_t)blockIdx.x * 16 * 64;
    for (int u = t; u < 1024; u += 256) ((float*)h_lds)[u] = h[base + u];
    __syncthreads();
    int wv = t >> 6, lane = t & 63;
    float aq[4] = {0,0,0,0}, ak[4] = {0,0,0,0}, av[4] = {0,0,0,0};
    for (int k = 0; k < 64; k++) {
        float wqv = WQ[k * 64 + lane], wkv = WK[k * 64 + lane], wvv = WV[k * 64 + lane];
#pragma unroll
        for (int r = 0; r < 4; r++) {
            float hv = h_lds[wv * 4 + r][k];
            aq[r] += hv * wqv; ak[r] += hv * wkv; av[r] += hv * wvv;
        }
    }
#pragma unroll
    for (int r = 0; r < 4; r++) {
        size_t o = base + (size_t)(wv * 4 + r) * 64 + lane;
        Q[o] = aq[r]; K[o] = ak[r]; V[o] = av[r];
    }
}

// ---------------- attention (wave per (b,h,i) row) ----------------
// grid 2048 x 256
__global__ __launch_bounds__(256) void k_attn(
    const float* __restrict__ Q, const float* __restrict__ K, const float* __restrict__ V,
    const float* __restrict__ biasL, const int* __restrict__ nmask,
    float* __restrict__ attO) {
    __shared__ float p_lds[4][512];
    int wv = threadIdx.x >> 6, lane = threadIdx.x & 63;
    int wid = blockIdx.x * 4 + wv;      // 0..8191
    int i = wid & 511;
    int bh = wid >> 9; int b = bh >> 2, hh = bh & 3;
    const float* qp = Q + ((size_t)(b * 512 + i)) * 64 + hh * 16;
    float4 q0 = *(const float4*)(qp);
    float4 q1 = *(const float4*)(qp + 4);
    float4 q2 = *(const float4*)(qp + 8);
    float4 q3 = *(const float4*)(qp + 12);
    const float* bias_row = biasL + ((size_t)(b * 4 + hh)) * NNSQ + (size_t)i * 512;
    float sc[8];
    float mmax = -3e38f;
#pragma unroll
    for (int c = 0; c < 8; c++) {
        int j = c * 64 + lane;
        const float* kp = K + ((size_t)(b * 512 + j)) * 64 + hh * 16;
        float4 k0 = *(const float4*)kp;
        float4 k1 = *(const float4*)(kp + 4);
        float4 k2 = *(const float4*)(kp + 8);
        float4 k3 = *(const float4*)(kp + 12);
        float s = q0.x*k0.x + q0.y*k0.y + q0.z*k0.z + q0.w*k0.w
                + q1.x*k1.x + q1.y*k1.y + q1.z*k1.z + q1.w*k1.w
                + q2.x*k2.x + q2.y*k2.y + q2.z*k2.z + q2.w*k2.w
                + q3.x*k3.x + q3.y*k3.y + q3.z*k3.z + q3.w*k3.w;
        s = s * 0.25f + bias_row[j];
        s = (nmask[b * 512 + j] != 0) ? s : -1e9f;
        sc[c] = s;
        mmax = fmaxf(mmax, s);
    }
    mmax = wmaxr(mmax);
    float sum = 0.f;
#pragma unroll
    for (int c = 0; c < 8; c++) { sc[c] = __expf(sc[c] - mmax); sum += sc[c]; }
    sum = wsum(sum);
    float inv = 1.0f / sum;
#pragma unroll
    for (int c = 0; c < 8; c++) p_lds[wv][c * 64 + lane] = sc[c] * inv;
    __syncthreads();
    int d = lane & 15, g = lane >> 4;
    float acc = 0.f;
    const float* vbase = V + ((size_t)b * 512) * 64 + hh * 16 + d;
    int j0 = g * 128;
#pragma unroll 4
    for (int j = j0; j < j0 + 128; j++) {
        acc += p_lds[wv][j] * vbase[(size_t)j * 64];
    }
    acc += __shfl_xor(acc, 16);
    acc += __shfl_xor(acc, 32);
    if (lane < 16) attO[((size_t)(b * 512 + i)) * 64 + hh * 16 + d] = acc;
}

// ---------------- output projection + residual + LN1 (in-place h) ----------------
// grid 512 x 256 : wave per row
__global__ __launch_bounds__(256) void k_oproj_ln1(
    const float* __restrict__ attO, const float* __restrict__ W, const float* __restrict__ Wb,
    const float* __restrict__ G, const float* __restrict__ Bt,
    float* __restrict__ h) {
    __shared__ float a_lds[4][64];
    int wv = threadIdx.x >> 6, lane = threadIdx.x & 63;
    int row = blockIdx.x * 4 + wv;
    a_lds[wv][lane] = attO[(size_t)row * 64 + lane];
    __syncthreads();
    float acc = Wb[lane];
#pragma unroll 8
    for (int k = 0; k < 64; k++) acc += a_lds[wv][k] * W[k * 64 + lane];
    float x = acc + h[(size_t)row * 64 + lane];
    float mn = wsum(x) * 0.015625f;
    float d = x - mn;
    float var = wsum(d * d) * 0.015625f;
    h[(size_t)row * 64 + lane] = d * rsqrtf(var + 1e-5f) * G[lane] + Bt[lane];
}

// ---------------- FFN + residual + LN2 (in-place h) ----------------
// grid 128 x 256 : block 16 rows, wave 4 rows
__global__ __launch_bounds__(256) void k_ffn(
    const float* __restrict__ W1, const float* __restrict__ B1,
    const float* __restrict__ W2, const float* __restrict__ B2,
    const float* __restrict__ G, const float* __restrict__ Bt,
    float* __restrict__ h) {
    __shared__ float h_lds[16][64];
    __shared__ float ff_lds[16][256];
    int t = threadIdx.x;
    size_t base = (size_t)blockIdx.x * 16 * 64;
    for (int u = t; u < 1024; u += 256) ((float*)h_lds)[u] = h[base + u];
    __syncthreads();
    int wv = t >> 6, lane = t & 63;
    float acc[4][4];
#pragma unroll
    for (int m = 0; m < 4; m++) {
        float bv = B1[m * 64 + lane];
#pragma unroll
        for (int r = 0; r < 4; r++) acc[m][r] = bv;
    }
    for (int k = 0; k < 64; k++) {
        float w0 = W1[k * 256 + lane], w1 = W1[k * 256 + 64 + lane],
              w2 = W1[k * 256 + 128 + lane], w3 = W1[k * 256 + 192 + lane];
#pragma unroll
        for (int r = 0; r < 4; r++) {
            float hv = h_lds[wv * 4 + r][k];
            acc[0][r] += hv * w0; acc[1][r] += hv * w1;
            acc[2][r] += hv * w2; acc[3][r] += hv * w3;
        }
    }
#pragma unroll
    for (int m = 0; m < 4; m++)
#pragma unroll
        for (int r = 0; r < 4; r++) {
            float u = acc[m][r];
            ff_lds[wv * 4 + r][m * 64 + lane] = 0.5f * u * (1.0f + erff(u * 0.70710678118654752f));
        }
    __syncthreads();
    float a2[4] = {0,0,0,0};
    for (int k = 0; k < 256; k++) {
        float w = W2[k * 64 + lane];
#pragma unroll
        for (int r = 0; r < 4; r++) a2[r] += ff_lds[wv * 4 + r][k] * w;
    }
    float b2v = B2[lane], gv = G[lane], btv = Bt[lane];
#pragma unroll
    for (int r = 0; r < 4; r++) {
        float x = a2[r] + b2v + h_lds[wv * 4 + r][lane];
        float mn = wsum(x) * 0.015625f;
        float d = x - mn;
        float var = wsum(d * d) * 0.015625f;
        h[base + (size_t)(wv * 4 + r) * 64 + lane] = d * rsqrtf(var + 1e-5f) * gv + btv;
    }
}

// ---------------- scoring head ----------------
// grid 511 x 256 : wave per candidate (b, j)
__global__ __launch_bounds__(256) void k_score(
    const float* __restrict__ h, const float* __restrict__ s1w, const float* __restrict__ s1b,
    const float* __restrict__ lng, const float* __restrict__ lnb,
    const float* __restrict__ s2w, const float* __restrict__ s2b,
    float* __restrict__ logits) {
    __shared__ float c_lds[4][128];
    int wv = threadIdx.x >> 6, lane = threadIdx.x & 63;
    int wid = blockIdx.x * 4 + wv;      // 0..2043
    int b = wid / 511; int jj = wid % 511; int j = jj + 1;
    c_lds[wv][lane]      = h[((size_t)b * 512) * 64 + lane];
    c_lds[wv][64 + lane] = h[((size_t)(b * 512 + j)) * 64 + lane];
    __syncthreads();
    float acc = s1b[lane];
#pragma unroll 8
    for (int k = 0; k < 128; k++) acc += c_lds[wv][k] * s1w[k * 64 + lane];
    float mn = wsum(acc) * 0.015625f;
    float d = acc - mn;
    float var = wsum(d * d) * 0.015625f;
    float x = d * rsqrtf(var + 1e-5f) * lng[lane] + lnb[lane];
    x = x >= 0.f ? x : 0.2f * x;
    float p = wsum(x * s2w[lane]);
    if (lane == 0) logits[wid] = p + s2b[0];
}

// ---------------- final softmax over candidates ----------------
// grid 4 x 512
__global__ __launch_bounds__(512) void k_probs(
    const float* __restrict__ logits, const int* __restrict__ nmask, float* __restrict__ out) {
    __shared__ float red[512];
    __shared__ int anyf;
    int b = blockIdx.x; int t = threadIdx.x;
    bool cand = false;
    if (t < 511) cand = nmask[b * 512 + 1 + t] != 0;
    if (t == 0) anyf = 0;
    __syncthreads();
    if (cand) atomicOr(&anyf, 1);
    __syncthreads();
    if (t == 0 && anyf == 0) cand = true;
    float val = -3e38f;
    if (t < 511) val = cand ? logits[b * 511 + t] : -1e9f;
    red[t] = val; __syncthreads();
    for (int s = 256; s > 0; s >>= 1) { if (t < s) red[t] = fmaxf(red[t], red[t + s]); __syncthreads(); }
    float m = red[0]; __syncthreads();
    float p = (t < 511) ? __expf(val - m) : 0.f;
    red[t] = p; __syncthreads();
    for (int s = 256; s > 0; s >>= 1) { if (t < s) red[t] += red[t + s]; __syncthreads(); }
    float inv = 1.0f / red[0];
    if (t < 511) out[b * 511 + t] = p * inv;
}

// ---------------- copy final h to output ----------------
__global__ void k_copy_h(const float4* __restrict__ src, float4* __restrict__ dst) {
    int i = blockIdx.x * 256 + threadIdx.x;   // 32768 float4
    dst[i] = src[i];
}

extern "C" void kernel_launch(void* const* d_in, const int* in_sizes, int n_in,
                              void* d_out, int out_size, void* d_ws, size_t ws_size,
                              hipStream_t stream) {
    const float* nf    = (const float*)d_in[0];
    const float* ef    = (const float*)d_in[1];
    const int*   nm    = (const int*)d_in[2];
    const int*   em    = (const int*)d_in[3];
    const float* npw   = (const float*)d_in[4];
    const float* npb   = (const float*)d_in[5];
    const float* epw   = (const float*)d_in[6];
    const float* epb   = (const float*)d_in[7];
    const float* wq    = (const float*)d_in[8];
    const float* wk    = (const float*)d_in[9];
    const float* wv    = (const float*)d_in[10];
    const float* eb1w  = (const float*)d_in[11];
    const float* eb1b  = (const float*)d_in[12];
    const float* eblng = (const float*)d_in[13];
    const float* eblnb = (const float*)d_in[14];
    const float* eb2w  = (const float*)d_in[15];
    const float* eb2b  = (const float*)d_in[16];
    const float* s1wv  = (const float*)d_in[17];  // spd1_w
    const float* s1bv  = (const float*)d_in[18];
    const float* s2wv  = (const float*)d_in[19];
    const float* s2bv  = (const float*)d_in[20];
    const float* wow   = (const float*)d_in[21];
    const float* wob   = (const float*)d_in[22];
    const float* ln1g  = (const float*)d_in[23];
    const float* ln1b  = (const float*)d_in[24];
    const float* ln2g  = (const float*)d_in[25];
    const float* ln2b  = (const float*)d_in[26];
    const float* f1w   = (const float*)d_in[27];
    const float* f1b   = (const float*)d_in[28];
    const float* f2w   = (const float*)d_in[29];
    const float* f2b   = (const float*)d_in[30];
    const float* sc1w  = (const float*)d_in[31];
    const float* sc1b  = (const float*)d_in[32];
    const float* sclng = (const float*)d_in[33];
    const float* sclnb = (const float*)d_in[34];
    const float* sc2w  = (const float*)d_in[35];
    const float* sc2b  = (const float*)d_in[36];

    char* W = (char*)d_ws;
    float*              bias    = (float*)(W + 0);                 // 50,331,648 B
    unsigned long long* adj     = (unsigned long long*)(W + 50331648); // 131,072 B
    unsigned char*      spd     = (unsigned char*)(W + 50462720);  // 1,048,576 B
    float*              table   = (float*)(W + 51511296);          // 1,024 B
    unsigned int*       counter = (unsigned int*)(W + 51512320);   // 256 B
    unsigned int*       elist   = (unsigned int*)(W + 51512576);   // 4,194,304 B
    float*              hbuf    = (float*)(W + 55706880);          // 524,288 B
    float*              Qb      = (float*)(W + 56231168);
    float*              Kb      = (float*)(W + 56755456);
    float*              Vb      = (float*)(W + 57279744);
    float*              attO    = (float*)(W + 57804032);
    float*              logits  = (float*)(W + 58328320);          // 8,176 B

    float* out = (float*)d_out;                 // [probs 2044][h 131072]

    hipMemsetAsync(counter, 0, 4, stream);
    k_adj<<<4096, 256, 0, stream>>>(em, adj);
    k_spd_table<<<1, 256, 0, stream>>>(s1wv, s1bv, s2wv, s2bv, table);
    k_bfs<<<2048, 64, 0, stream>>>(adj, spd);
    k_fill_bias<<<4096, 256, 0, stream>>>(spd, table, bias);
    k_compact<<<4096, 256, 0, stream>>>(em, counter, elist);
    k_edge_bias<<<dim3(4096, 3), 256, 0, stream>>>(ef, counter, elist, epw, epb,
                                                   eb1w, eb1b, eblng, eblnb, eb2w, eb2b, bias);
    k_node_proj<<<512, 256, 0, stream>>>(nf, npw, npb, hbuf);

    for (int l = 0; l < LL; l++) {
        k_qkv<<<128, 256, 0, stream>>>(hbuf, wq + l * 4096, wk + l * 4096, wv + l * 4096,
                                       Qb, Kb, Vb);
        k_attn<<<2048, 256, 0, stream>>>(Qb, Kb, Vb, bias + (size_t)l * 16 * NNSQ, nm, attO);
        k_oproj_ln1<<<512, 256, 0, stream>>>(attO, wow + l * 4096, wob + l * 64,
                                             ln1g + l * 64, ln1b + l * 64, hbuf);
        k_ffn<<<128, 256, 0, stream>>>(f1w + l * 16384, f1b + l * 256,
                                       f2w + l * 16384, f2b + l * 64,
                                       ln2g + l * 64, ln2b + l * 64, hbuf);
    }

    k_score<<<511, 256, 0, stream>>>(hbuf, sc1w, sc1b, sclng, sclnb, sc2w, sc2b, logits);
    k_copy_h<<<128, 256, 0, stream>>>((const float4*)hbuf, (float4*)(out + 2044));
    k_probs<<<4, 512, 0, stream>>>(logits, nm, out);
}

// Round 2
// 453.528 us; speedup vs baseline: 1.3906x; 1.3906x over previous
//
#include <hip/hip_runtime.h>
#include <math.h>

// Problem constants
#define BB 4
#define NN 512
#define HH 64
#define NHH 4
#define HDD 16
#define LL 3
#define NNSQ 262144          // N*N
#define FFF 256

// ---------------- wave helpers ----------------
__device__ __forceinline__ float wsum(float x) {
#pragma unroll
    for (int o = 1; o < 64; o <<= 1) x += __shfl_xor(x, o);
    return x;
}
__device__ __forceinline__ float wmaxr(float x) {
#pragma unroll
    for (int o = 1; o < 64; o <<= 1) x = fmaxf(x, __shfl_xor(x, o));
    return x;
}

// ---------------- adjacency bitsets ----------------
// grid 4096 x 256 : wave per (row, 64-col chunk)
__global__ void k_adj(const int* __restrict__ em, unsigned long long* __restrict__ adj) {
    int wid = blockIdx.x * 4 + (threadIdx.x >> 6);
    int lane = threadIdx.x & 63;
    int chunk = wid & 7;
    int row = wid >> 3;                 // b*N + i
    int j = chunk * 64 + lane;
    int v = em[(size_t)row * NN + j];
    unsigned long long bal = __ballot(v != 0);
    if (lane == 0) adj[row * 8 + chunk] = bal;
}

// ---------------- spd bias lookup table [l][v][h], v in 0..10 ----------------
__global__ void k_spd_table(const float* __restrict__ s1w, const float* __restrict__ s1b,
                            const float* __restrict__ s2w, const float* __restrict__ s2b,
                            float* __restrict__ table) {
    int t = threadIdx.x;
    if (t >= 132) return;
    int l = t / 44; int r = t % 44; int v = r / 4; int hh = r % 4;
    float x = (float)v * 0.1f;
    float acc = s2b[l * 4 + hh];
#pragma unroll
    for (int c = 0; c < 16; c++) {
        float tt = x * s1w[l * 16 + c] + s1b[l * 16 + c];
        tt = tt >= 0.f ? tt : 0.2f * tt;
        acc += tt * s2w[(l * 16 + c) * 4 + hh];
    }
    table[t] = acc;
}

// ---------------- BFS (levels 1..9, >=10 -> 10) ----------------
// grid 2048 x 64 : one wave per source row
__global__ void k_bfs(const unsigned long long* __restrict__ adj, unsigned char* __restrict__ spd) {
    __shared__ unsigned long long vis[8], fro[8], nxt[8];
    __shared__ unsigned long long dist8[64];
    unsigned char* dist = (unsigned char*)dist8;
    int t = threadIdx.x;
    int row = blockIdx.x;               // b*N + i
    int b = row >> 9; int src = row & 511;
    dist8[t] = 0x0A0A0A0A0A0A0A0AULL;   // init all to 10
    if (t < 8) { vis[t] = 0ULL; fro[t] = 0ULL; }
    __syncthreads();
    if (t == 0) {
        dist[src] = 0;
        vis[src >> 6] = 1ULL << (src & 63);
        fro[src >> 6] = 1ULL << (src & 63);
    }
    __syncthreads();
    const unsigned long long* arow = adj + (size_t)b * NN * 8;
    for (int d = 1; d <= 9; d++) {
        if (t < 8) nxt[t] = 0ULL;
        __syncthreads();
        int c = t >> 3, w = t & 7;
        unsigned long long f = fro[c];
        unsigned long long acc = 0ULL;
        while (f) {
            int k = (c << 6) + __builtin_ctzll(f);
            f &= f - 1;
            acc |= arow[k * 8 + w];
        }
        if (acc) atomicOr(&nxt[w], acc);
        __syncthreads();
        if (t < 8) {
            unsigned long long nw = nxt[t] & ~vis[t];
            vis[t] |= nw;
            fro[t] = nw;
            while (nw) {
                int j = (t << 6) + __builtin_ctzll(nw);
                nw &= nw - 1;
                dist[j] = (unsigned char)d;
            }
        }
        __syncthreads();
    }
    ((unsigned long long*)(spd + (size_t)row * NN))[t] = dist8[t];
}

// ---------------- fill bias tensor with spd-bias ----------------
// grid 4096 x 256 : thread per (b,i,j)
__global__ void k_fill_bias(const unsigned char* __restrict__ spd, const float* __restrict__ table,
                            float* __restrict__ bias) {
    __shared__ float tab[132];
    int t = threadIdx.x;
    if (t < 132) tab[t] = table[t];
    __syncthreads();
    int idx = blockIdx.x * 256 + t;     // (b*N+i)*N + j
    int v = spd[idx];
    int b = idx >> 18; int ij = idx & (NNSQ - 1);
#pragma unroll
    for (int l = 0; l < 3; l++)
#pragma unroll
        for (int hh = 0; hh < 4; hh++)
            bias[(size_t)((l * 4 + b) * 4 + hh) * NNSQ + ij] = tab[(l * 11 + v) * 4 + hh];
}

// ---------------- compaction: count -> scan -> scatter (no contended atomics) ----------------
// grid 4096 x 256
__global__ void k_count(const int* __restrict__ em, unsigned int* __restrict__ blockCnt) {
    __shared__ unsigned int wc[4];
    int t = threadIdx.x;
    int idx = blockIdx.x * 256 + t;
    bool m = em[idx] != 0;
    unsigned long long bal = __ballot(m);
    if ((t & 63) == 0) wc[t >> 6] = (unsigned int)__popcll(bal);
    __syncthreads();
    if (t == 0) blockCnt[blockIdx.x] = wc[0] + wc[1] + wc[2] + wc[3];
}

// 1 block x 1024 : exclusive prefix over 4096 block counts
__global__ __launch_bounds__(1024) void k_scan(const unsigned int* __restrict__ blockCnt,
                                               unsigned int* __restrict__ blockOff,
                                               unsigned int* __restrict__ counter) {
    __shared__ unsigned int part[1024];
    int t = threadIdx.x;
    unsigned int v0 = blockCnt[t * 4], v1 = blockCnt[t * 4 + 1],
                 v2 = blockCnt[t * 4 + 2], v3 = blockCnt[t * 4 + 3];
    unsigned int s = v0 + v1 + v2 + v3;
    part[t] = s;
    __syncthreads();
    for (int o = 1; o < 1024; o <<= 1) {
        unsigned int add = (t >= o) ? part[t - o] : 0u;
        __syncthreads();
        part[t] += add;
        __syncthreads();
    }
    unsigned int excl = part[t] - s;
    blockOff[t * 4]     = excl;
    blockOff[t * 4 + 1] = excl + v0;
    blockOff[t * 4 + 2] = excl + v0 + v1;
    blockOff[t * 4 + 3] = excl + v0 + v1 + v2;
    if (t == 1023) counter[0] = part[t];
}

// grid 4096 x 256
__global__ void k_scatter(const int* __restrict__ em, const unsigned int* __restrict__ blockOff,
                          unsigned int* __restrict__ elist) {
    __shared__ unsigned int wc[4];
    int t = threadIdx.x; int lane = t & 63; int wv = t >> 6;
    int idx = blockIdx.x * 256 + t;
    bool m = em[idx] != 0;
    unsigned long long bal = __ballot(m);
    if (lane == 0) wc[wv] = (unsigned int)__popcll(bal);
    __syncthreads();
    unsigned int base = blockOff[blockIdx.x];
    for (int w = 0; w < wv; w++) base += wc[w];
    if (m) {
        int pre = __popcll(bal & ((1ULL << lane) - 1ULL));
        elist[base + pre] = (unsigned int)idx;
    }
}

// ---------------- edge bias MLP at true edges ----------------
// grid (4096, 3) x 256 : thread per (edge, layer)
__global__ __launch_bounds__(256) void k_edge_bias(
    const float* __restrict__ ef, const unsigned int* __restrict__ counter,
    const unsigned int* __restrict__ elist,
    const float* __restrict__ epw, const float* __restrict__ epb,
    const float* __restrict__ eb1w, const float* __restrict__ eb1b,
    const float* __restrict__ lng, const float* __restrict__ lnb,
    const float* __restrict__ eb2w, const float* __restrict__ eb2b,
    float* __restrict__ bias) {
    unsigned int count = *counter;
    unsigned int idx = blockIdx.x * 256 + threadIdx.x;
    if (idx >= count) return;
    int l = blockIdx.y;
    unsigned int pos = elist[idx];      // b*N*N + i*N + j
    int b = pos >> 18; int ij = pos & (NNSQ - 1);
    const float* e7 = ef + (size_t)pos * 7;
    float f0 = e7[0], f1 = e7[1], f2 = e7[2], f3 = e7[3], f4 = e7[4], f5 = e7[5], f6 = e7[6];
    float tt[16];
#pragma unroll
    for (int c = 0; c < 16; c++) tt[c] = eb1b[l * 16 + c];
    const float* W1 = eb1w + l * 1024;
    for (int k = 0; k < 64; k++) {
        float ek = epb[k] + f0 * epw[k] + f1 * epw[64 + k] + f2 * epw[128 + k] + f3 * epw[192 + k]
                 + f4 * epw[256 + k] + f5 * epw[320 + k] + f6 * epw[384 + k];
#pragma unroll
        for (int c = 0; c < 16; c++) tt[c] += ek * W1[k * 16 + c];
    }
    float m = 0.f;
#pragma unroll
    for (int c = 0; c < 16; c++) m += tt[c];
    m *= 0.0625f;
    float var = 0.f;
#pragma unroll
    for (int c = 0; c < 16; c++) { float d = tt[c] - m; var += d * d; }
    var *= 0.0625f;
    float inv = rsqrtf(var + 1e-5f);
#pragma unroll
    for (int c = 0; c < 16; c++) {
        float x = (tt[c] - m) * inv * lng[l * 16 + c] + lnb[l * 16 + c];
        tt[c] = x >= 0.f ? x : 0.2f * x;
    }
#pragma unroll
    for (int hh = 0; hh < 4; hh++) {
        float a = eb2b[l * 4 + hh];
#pragma unroll
        for (int c = 0; c < 16; c++) a += tt[c] * eb2w[(l * 16 + c) * 4 + hh];
        bias[(size_t)((l * 4 + b) * 4 + hh) * NNSQ + ij] = a;
    }
}

// ---------------- node projection ----------------
// grid 512 x 256 : wave per row
__global__ void k_node_proj(const float* __restrict__ nf, const float* __restrict__ w,
                            const float* __restrict__ bb, float* __restrict__ h) {
    int wid = blockIdx.x * 4 + (threadIdx.x >> 6);
    int f = threadIdx.x & 63;
    const float* r = nf + (size_t)wid * 18;
    float acc = bb[f];
#pragma unroll
    for (int c = 0; c < 18; c++) acc += r[c] * w[c * 64 + f];
    h[(size_t)wid * 64 + f] = acc;
}

// ---------------- QKV projection (no bias in reference) ----------------
// grid 128 x 256 : block handles 16 rows, wave handles 4 rows
__global__ __launch_bounds__(256) void k_qkv(
    const float* __restrict__ h,
    const float* __restrict__ WQ, const float* __restrict__ WK, const float* __restrict__ WV,
    float* __restrict__ Q, float* __restrict__ K, float* __restrict__ V) {
    __shared__ float h_lds[16][64];
    int t = threadIdx.x;
    size_t base = (size_t)blockIdx.x * 16 * 64;
    for (int u = t; u < 1024; u += 256) ((float*)h_lds)[u] = h[base + u];
    __syncthreads();
    int wv = t >> 6, lane = t & 63;
    float aq[4] = {0,0,0,0}, ak[4] = {0,0,0,0}, av[4] = {0,0,0,0};
    for (int k = 0; k < 64; k++) {
        float wqv = WQ[k * 64 + lane], wkv = WK[k * 64 + lane], wvv = WV[k * 64 + lane];
#pragma unroll
        for (int r = 0; r < 4; r++) {
            float hv = h_lds[wv * 4 + r][k];
            aq[r] += hv * wqv; ak[r] += hv * wkv; av[r] += hv * wvv;
        }
    }
#pragma unroll
    for (int r = 0; r < 4; r++) {
        size_t o = base + (size_t)(wv * 4 + r) * 64 + lane;
        Q[o] = aq[r]; K[o] = ak[r]; V[o] = av[r];
    }
}

// ---------------- attention (wave per (b,h,i) row) ----------------
// grid 2048 x 256
__global__ __launch_bounds__(256) void k_attn(
    const float* __restrict__ Q, const float* __restrict__ K, const float* __restrict__ V,
    const float* __restrict__ biasL, const int* __restrict__ nmask,
    float* __restrict__ attO) {
    __shared__ float p_lds[4][512];
    int wv = threadIdx.x >> 6, lane = threadIdx.x & 63;
    int wid = blockIdx.x * 4 + wv;      // 0..8191
    int i = wid & 511;
    int bh = wid >> 9; int b = bh >> 2, hh = bh & 3;
    const float* qp = Q + ((size_t)(b * 512 + i)) * 64 + hh * 16;
    float4 q0 = *(const float4*)(qp);
    float4 q1 = *(const float4*)(qp + 4);
    float4 q2 = *(const float4*)(qp + 8);
    float4 q3 = *(const float4*)(qp + 12);
    const float* bias_row = biasL + ((size_t)(b * 4 + hh)) * NNSQ + (size_t)i * 512;
    float sc[8];
    float mmax = -3e38f;
#pragma unroll
    for (int c = 0; c < 8; c++) {
        int j = c * 64 + lane;
        const float* kp = K + ((size_t)(b * 512 + j)) * 64 + hh * 16;
        float4 k0 = *(const float4*)kp;
        float4 k1 = *(const float4*)(kp + 4);
        float4 k2 = *(const float4*)(kp + 8);
        float4 k3 = *(const float4*)(kp + 12);
        float s = q0.x*k0.x + q0.y*k0.y + q0.z*k0.z + q0.w*k0.w
                + q1.x*k1.x + q1.y*k1.y + q1.z*k1.z + q1.w*k1.w
                + q2.x*k2.x + q2.y*k2.y + q2.z*k2.z + q2.w*k2.w
                + q3.x*k3.x + q3.y*k3.y + q3.z*k3.z + q3.w*k3.w;
        s = s * 0.25f + bias_row[j];
        s = (nmask[b * 512 + j] != 0) ? s : -1e9f;
        sc[c] = s;
        mmax = fmaxf(mmax, s);
    }
    mmax = wmaxr(mmax);
    float sum = 0.f;
#pragma unroll
    for (int c = 0; c < 8; c++) { sc[c] = __expf(sc[c] - mmax); sum += sc[c]; }
    sum = wsum(sum);
    float inv = 1.0f / sum;
#pragma unroll
    for (int c = 0; c < 8; c++) p_lds[wv][c * 64 + lane] = sc[c] * inv;
    __syncthreads();
    int d = lane & 15, g = lane >> 4;
    float acc = 0.f;
    const float* vbase = V + ((size_t)b * 512) * 64 + hh * 16 + d;
    int j0 = g * 128;
#pragma unroll 4
    for (int j = j0; j < j0 + 128; j++) {
        acc += p_lds[wv][j] * vbase[(size_t)j * 64];
    }
    acc += __shfl_xor(acc, 16);
    acc += __shfl_xor(acc, 32);
    if (lane < 16) attO[((size_t)(b * 512 + i)) * 64 + hh * 16 + d] = acc;
}

// ---------------- output projection + residual + LN1 (in-place h) ----------------
// grid 512 x 256 : wave per row
__global__ __launch_bounds__(256) void k_oproj_ln1(
    const float* __restrict__ attO, const float* __restrict__ W, const float* __restrict__ Wb,
    const float* __restrict__ G, const float* __restrict__ Bt,
    float* __restrict__ h) {
    __shared__ float a_lds[4][64];
    int wv = threadIdx.x >> 6, lane = threadIdx.x & 63;
    int row = blockIdx.x * 4 + wv;
    a_lds[wv][lane] = attO[(size_t)row * 64 + lane];
    __syncthreads();
    float acc = Wb[lane];
#pragma unroll 8
    for (int k = 0; k < 64; k++) acc += a_lds[wv][k] * W[k * 64 + lane];
    float x = acc + h[(size_t)row * 64 + lane];
    float mn = wsum(x) * 0.015625f;
    float d = x - mn;
    float var = wsum(d * d) * 0.015625f;
    h[(size_t)row * 64 + lane] = d * rsqrtf(var + 1e-5f) * G[lane] + Bt[lane];
}

// ---------------- FFN + residual + LN2 (in-place h) ----------------
// grid 128 x 256 : block 16 rows, wave 4 rows
__global__ __launch_bounds__(256) void k_ffn(
    const float* __restrict__ W1, const float* __restrict__ B1,
    const float* __restrict__ W2, const float* __restrict__ B2,
    const float* __restrict__ G, const float* __restrict__ Bt,
    float* __restrict__ h) {
    __shared__ float h_lds[16][64];
    __shared__ float ff_lds[16][256];
    int t = threadIdx.x;
    size_t base = (size_t)blockIdx.x * 16 * 64;
    for (int u = t; u < 1024; u += 256) ((float*)h_lds)[u] = h[base + u];
    __syncthreads();
    int wv = t >> 6, lane = t & 63;
    float acc[4][4];
#pragma unroll
    for (int m = 0; m < 4; m++) {
        float bv = B1[m * 64 + lane];
#pragma unroll
        for (int r = 0; r < 4; r++) acc[m][r] = bv;
    }
    for (int k = 0; k < 64; k++) {
        float w0 = W1[k * 256 + lane], w1 = W1[k * 256 + 64 + lane],
              w2 = W1[k * 256 + 128 + lane], w3 = W1[k * 256 + 192 + lane];
#pragma unroll
        for (int r = 0; r < 4; r++) {
            float hv = h_lds[wv * 4 + r][k];
            acc[0][r] += hv * w0; acc[1][r] += hv * w1;
            acc[2][r] += hv * w2; acc[3][r] += hv * w3;
        }
    }
#pragma unroll
    for (int m = 0; m < 4; m++)
#pragma unroll
        for (int r = 0; r < 4; r++) {
            float u = acc[m][r];
            ff_lds[wv * 4 + r][m * 64 + lane] = 0.5f * u * (1.0f + erff(u * 0.70710678118654752f));
        }
    __syncthreads();
    float a2[4] = {0,0,0,0};
    for (int k = 0; k < 256; k++) {
        float w = W2[k * 64 + lane];
#pragma unroll
        for (int r = 0; r < 4; r++) a2[r] += ff_lds[wv * 4 + r][k] * w;
    }
    float b2v = B2[lane], gv = G[lane], btv = Bt[lane];
#pragma unroll
    for (int r = 0; r < 4; r++) {
        float x = a2[r] + b2v + h_lds[wv * 4 + r][lane];
        float mn = wsum(x) * 0.015625f;
        float d = x - mn;
        float var = wsum(d * d) * 0.015625f;
        h[base + (size_t)(wv * 4 + r) * 64 + lane] = d * rsqrtf(var + 1e-5f) * gv + btv;
    }
}

// ---------------- scoring head ----------------
// grid 511 x 256 : wave per candidate (b, j)
__global__ __launch_bounds__(256) void k_score(
    const float* __restrict__ h, const float* __restrict__ s1w, const float* __restrict__ s1b,
    const float* __restrict__ lng, const float* __restrict__ lnb,
    const float* __restrict__ s2w, const float* __restrict__ s2b,
    float* __restrict__ logits) {
    __shared__ float c_lds[4][128];
    int wv = threadIdx.x >> 6, lane = threadIdx.x & 63;
    int wid = blockIdx.x * 4 + wv;      // 0..2043
    int b = wid / 511; int jj = wid % 511; int j = jj + 1;
    c_lds[wv][lane]      = h[((size_t)b * 512) * 64 + lane];
    c_lds[wv][64 + lane] = h[((size_t)(b * 512 + j)) * 64 + lane];
    __syncthreads();
    float acc = s1b[lane];
#pragma unroll 8
    for (int k = 0; k < 128; k++) acc += c_lds[wv][k] * s1w[k * 64 + lane];
    float mn = wsum(acc) * 0.015625f;
    float d = acc - mn;
    float var = wsum(d * d) * 0.015625f;
    float x = d * rsqrtf(var + 1e-5f) * lng[lane] + lnb[lane];
    x = x >= 0.f ? x : 0.2f * x;
    float p = wsum(x * s2w[lane]);
    if (lane == 0) logits[wid] = p + s2b[0];
}

// ---------------- final softmax over candidates ----------------
// grid 4 x 512
__global__ __launch_bounds__(512) void k_probs(
    const float* __restrict__ logits, const int* __restrict__ nmask, float* __restrict__ out) {
    __shared__ float red[512];
    __shared__ int anyf;
    int b = blockIdx.x; int t = threadIdx.x;
    bool cand = false;
    if (t < 511) cand = nmask[b * 512 + 1 + t] != 0;
    if (t == 0) anyf = 0;
    __syncthreads();
    if (cand) atomicOr(&anyf, 1);
    __syncthreads();
    if (t == 0 && anyf == 0) cand = true;
    float val = -3e38f;
    if (t < 511) val = cand ? logits[b * 511 + t] : -1e9f;
    red[t] = val; __syncthreads();
    for (int s = 256; s > 0; s >>= 1) { if (t < s) red[t] = fmaxf(red[t], red[t + s]); __syncthreads(); }
    float m = red[0]; __syncthreads();
    float p = (t < 511) ? __expf(val - m) : 0.f;
    red[t] = p; __syncthreads();
    for (int s = 256; s > 0; s >>= 1) { if (t < s) red[t] += red[t + s]; __syncthreads(); }
    float inv = 1.0f / red[0];
    if (t < 511) out[b * 511 + t] = p * inv;
}

// ---------------- copy final h to output ----------------
__global__ void k_copy_h(const float4* __restrict__ src, float4* __restrict__ dst) {
    int i = blockIdx.x * 256 + threadIdx.x;   // 32768 float4
    dst[i] = src[i];
}

extern "C" void kernel_launch(void* const* d_in, const int* in_sizes, int n_in,
                              void* d_out, int out_size, void* d_ws, size_t ws_size,
                              hipStream_t stream) {
    const float* nf    = (const float*)d_in[0];
    const float* ef    = (const float*)d_in[1];
    const int*   nm    = (const int*)d_in[2];
    const int*   em    = (const int*)d_in[3];
    const float* npw   = (const float*)d_in[4];
    const float* npb   = (const float*)d_in[5];
    const float* epw   = (const float*)d_in[6];
    const float* epb   = (const float*)d_in[7];
    const float* wq    = (const float*)d_in[8];
    const float* wk    = (const float*)d_in[9];
    const float* wv    = (const float*)d_in[10];
    const float* eb1w  = (const float*)d_in[11];
    const float* eb1b  = (const float*)d_in[12];
    const float* eblng = (const float*)d_in[13];
    const float* eblnb = (const float*)d_in[14];
    const float* eb2w  = (const float*)d_in[15];
    const float* eb2b  = (const float*)d_in[16];
    const float* s1wv  = (const float*)d_in[17];  // spd1_w
    const float* s1bv  = (const float*)d_in[18];
    const float* s2wv  = (const float*)d_in[19];
    const float* s2bv  = (const float*)d_in[20];
    const float* wow   = (const float*)d_in[21];
    const float* wob   = (const float*)d_in[22];
    const float* ln1g  = (const float*)d_in[23];
    const float* ln1b  = (const float*)d_in[24];
    const float* ln2g  = (const float*)d_in[25];
    const float* ln2b  = (const float*)d_in[26];
    const float* f1w   = (const float*)d_in[27];
    const float* f1b   = (const float*)d_in[28];
    const float* f2w   = (const float*)d_in[29];
    const float* f2b   = (const float*)d_in[30];
    const float* sc1w  = (const float*)d_in[31];
    const float* sc1b  = (const float*)d_in[32];
    const float* sclng = (const float*)d_in[33];
    const float* sclnb = (const float*)d_in[34];
    const float* sc2w  = (const float*)d_in[35];
    const float* sc2b  = (const float*)d_in[36];

    char* W = (char*)d_ws;
    float*              bias    = (float*)(W + 0);                 // 50,331,648 B
    unsigned long long* adj     = (unsigned long long*)(W + 50331648); // 131,072 B
    unsigned char*      spd     = (unsigned char*)(W + 50462720);  // 1,048,576 B
    float*              table   = (float*)(W + 51511296);          // 1,024 B
    unsigned int*       counter = (unsigned int*)(W + 51512320);   // 256 B
    unsigned int*       elist   = (unsigned int*)(W + 51512576);   // 4,194,304 B
    float*              hbuf    = (float*)(W + 55706880);          // 524,288 B
    float*              Qb      = (float*)(W + 56231168);
    float*              Kb      = (float*)(W + 56755456);
    float*              Vb      = (float*)(W + 57279744);
    float*              attO    = (float*)(W + 57804032);
    float*              logits  = (float*)(W + 58328320);          // 8,176 B
    unsigned int*       blockCnt= (unsigned int*)(W + 58337280);   // 16,384 B
    unsigned int*       blockOff= (unsigned int*)(W + 58353664);   // 16,384 B

    float* out = (float*)d_out;                 // [probs 2044][h 131072]

    k_adj<<<4096, 256, 0, stream>>>(em, adj);
    k_spd_table<<<1, 256, 0, stream>>>(s1wv, s1bv, s2wv, s2bv, table);
    k_bfs<<<2048, 64, 0, stream>>>(adj, spd);
    k_fill_bias<<<4096, 256, 0, stream>>>(spd, table, bias);
    k_count<<<4096, 256, 0, stream>>>(em, blockCnt);
    k_scan<<<1, 1024, 0, stream>>>(blockCnt, blockOff, counter);
    k_scatter<<<4096, 256, 0, stream>>>(em, blockOff, elist);
    k_edge_bias<<<dim3(4096, 3), 256, 0, stream>>>(ef, counter, elist, epw, epb,
                                                   eb1w, eb1b, eblng, eblnb, eb2w, eb2b, bias);
    k_node_proj<<<512, 256, 0, stream>>>(nf, npw, npb, hbuf);

    for (int l = 0; l < LL; l++) {
        k_qkv<<<128, 256, 0, stream>>>(hbuf, wq + l * 4096, wk + l * 4096, wv + l * 4096,
                                       Qb, Kb, Vb);
        k_attn<<<2048, 256, 0, stream>>>(Qb, Kb, Vb, bias + (size_t)l * 16 * NNSQ, nm, attO);
        k_oproj_ln1<<<512, 256, 0, stream>>>(attO, wow + l * 4096, wob + l * 64,
                                             ln1g + l * 64, ln1b + l * 64, hbuf);
        k_ffn<<<128, 256, 0, stream>>>(f1w + l * 16384, f1b + l * 256,
                                       f2w + l * 16384, f2b + l * 64,
                                       ln2g + l * 64, ln2b + l * 64, hbuf);
    }

    k_score<<<511, 256, 0, stream>>>(hbuf, sc1w, sc1b, sclng, sclnb, sc2w, sc2b, logits);
    k_copy_h<<<128, 256, 0, stream>>>((const float4*)hbuf, (float4*)(out + 2044));
    k_probs<<<4, 512, 0, stream>>>(logits, nm, out);
}

// Round 3
// 359.966 us; speedup vs baseline: 1.7520x; 1.2599x over previous
//
#include <hip/hip_runtime.h>
#include <math.h>

// Problem constants
#define BB 4
#define NN 512
#define HH 64
#define NHH 4
#define HDD 16
#define LL 3
#define NNSQ 262144          // N*N
#define FFF 256

// ---------------- wave helpers ----------------
__device__ __forceinline__ float wsum(float x) {
#pragma unroll
    for (int o = 1; o < 64; o <<= 1) x += __shfl_xor(x, o);
    return x;
}
__device__ __forceinline__ float wmaxr(float x) {
#pragma unroll
    for (int o = 1; o < 64; o <<= 1) x = fmaxf(x, __shfl_xor(x, o));
    return x;
}

// ---------------- adjacency bitsets ----------------
// grid 4096 x 256 : wave per (row, 64-col chunk)
__global__ void k_adj(const int* __restrict__ em, unsigned long long* __restrict__ adj) {
    int wid = blockIdx.x * 4 + (threadIdx.x >> 6);
    int lane = threadIdx.x & 63;
    int chunk = wid & 7;
    int row = wid >> 3;                 // b*N + i
    int j = chunk * 64 + lane;
    int v = em[(size_t)row * NN + j];
    unsigned long long bal = __ballot(v != 0);
    if (lane == 0) adj[row * 8 + chunk] = bal;
}

// ---------------- spd bias lookup table [l][v][h], v in 0..10 ----------------
__global__ void k_spd_table(const float* __restrict__ s1w, const float* __restrict__ s1b,
                            const float* __restrict__ s2w, const float* __restrict__ s2b,
                            float* __restrict__ table) {
    int t = threadIdx.x;
    if (t >= 132) return;
    int l = t / 44; int r = t % 44; int v = r / 4; int hh = r % 4;
    float x = (float)v * 0.1f;
    float acc = s2b[l * 4 + hh];
#pragma unroll
    for (int c = 0; c < 16; c++) {
        float tt = x * s1w[l * 16 + c] + s1b[l * 16 + c];
        tt = tt >= 0.f ? tt : 0.2f * tt;
        acc += tt * s2w[(l * 16 + c) * 4 + hh];
    }
    table[t] = acc;
}

// ---------------- BFS (levels 1..9, >=10 -> 10) ----------------
// grid 2048 x 64 : one wave per source row
__global__ void k_bfs(const unsigned long long* __restrict__ adj, unsigned char* __restrict__ spd) {
    __shared__ unsigned long long vis[8], fro[8], nxt[8];
    __shared__ unsigned long long dist8[64];
    unsigned char* dist = (unsigned char*)dist8;
    int t = threadIdx.x;
    int row = blockIdx.x;               // b*N + i
    int b = row >> 9; int src = row & 511;
    dist8[t] = 0x0A0A0A0A0A0A0A0AULL;   // init all to 10
    if (t < 8) { vis[t] = 0ULL; fro[t] = 0ULL; }
    __syncthreads();
    if (t == 0) {
        dist[src] = 0;
        vis[src >> 6] = 1ULL << (src & 63);
        fro[src >> 6] = 1ULL << (src & 63);
    }
    __syncthreads();
    const unsigned long long* arow = adj + (size_t)b * NN * 8;
    for (int d = 1; d <= 9; d++) {
        if (t < 8) nxt[t] = 0ULL;
        __syncthreads();
        int c = t >> 3, w = t & 7;
        unsigned long long f = fro[c];
        unsigned long long acc = 0ULL;
        while (f) {
            int k = (c << 6) + __builtin_ctzll(f);
            f &= f - 1;
            acc |= arow[k * 8 + w];
        }
        if (acc) atomicOr(&nxt[w], acc);
        __syncthreads();
        if (t < 8) {
            unsigned long long nw = nxt[t] & ~vis[t];
            vis[t] |= nw;
            fro[t] = nw;
            while (nw) {
                int j = (t << 6) + __builtin_ctzll(nw);
                nw &= nw - 1;
                dist[j] = (unsigned char)d;
            }
        }
        __syncthreads();
    }
    ((unsigned long long*)(spd + (size_t)row * NN))[t] = dist8[t];
}

// ---------------- fill bias tensor with spd-bias ----------------
// grid 4096 x 256 : thread per (b,i,j)
__global__ void k_fill_bias(const unsigned char* __restrict__ spd, const float* __restrict__ table,
                            float* __restrict__ bias) {
    __shared__ float tab[132];
    int t = threadIdx.x;
    if (t < 132) tab[t] = table[t];
    __syncthreads();
    int idx = blockIdx.x * 256 + t;     // (b*N+i)*N + j
    int v = spd[idx];
    int b = idx >> 18; int ij = idx & (NNSQ - 1);
#pragma unroll
    for (int l = 0; l < 3; l++)
#pragma unroll
        for (int hh = 0; hh < 4; hh++)
            bias[(size_t)((l * 4 + b) * 4 + hh) * NNSQ + ij] = tab[(l * 11 + v) * 4 + hh];
}

// ---------------- compaction: count -> scan -> scatter (no contended atomics) ----------------
// grid 4096 x 256
__global__ void k_count(const int* __restrict__ em, unsigned int* __restrict__ blockCnt) {
    __shared__ unsigned int wc[4];
    int t = threadIdx.x;
    int idx = blockIdx.x * 256 + t;
    bool m = em[idx] != 0;
    unsigned long long bal = __ballot(m);
    if ((t & 63) == 0) wc[t >> 6] = (unsigned int)__popcll(bal);
    __syncthreads();
    if (t == 0) blockCnt[blockIdx.x] = wc[0] + wc[1] + wc[2] + wc[3];
}

// 1 block x 1024 : exclusive prefix over 4096 block counts
__global__ __launch_bounds__(1024) void k_scan(const unsigned int* __restrict__ blockCnt,
                                               unsigned int* __restrict__ blockOff,
                                               unsigned int* __restrict__ counter) {
    __shared__ unsigned int part[1024];
    int t = threadIdx.x;
    unsigned int v0 = blockCnt[t * 4], v1 = blockCnt[t * 4 + 1],
                 v2 = blockCnt[t * 4 + 2], v3 = blockCnt[t * 4 + 3];
    unsigned int s = v0 + v1 + v2 + v3;
    part[t] = s;
    __syncthreads();
    for (int o = 1; o < 1024; o <<= 1) {
        unsigned int add = (t >= o) ? part[t - o] : 0u;
        __syncthreads();
        part[t] += add;
        __syncthreads();
    }
    unsigned int excl = part[t] - s;
    blockOff[t * 4]     = excl;
    blockOff[t * 4 + 1] = excl + v0;
    blockOff[t * 4 + 2] = excl + v0 + v1;
    blockOff[t * 4 + 3] = excl + v0 + v1 + v2;
    if (t == 1023) counter[0] = part[t];
}

// grid 4096 x 256
__global__ void k_scatter(const int* __restrict__ em, const unsigned int* __restrict__ blockOff,
                          unsigned int* __restrict__ elist) {
    __shared__ unsigned int wc[4];
    int t = threadIdx.x; int lane = t & 63; int wv = t >> 6;
    int idx = blockIdx.x * 256 + t;
    bool m = em[idx] != 0;
    unsigned long long bal = __ballot(m);
    if (lane == 0) wc[wv] = (unsigned int)__popcll(bal);
    __syncthreads();
    unsigned int base = blockOff[blockIdx.x];
    for (int w = 0; w < wv; w++) base += wc[w];
    if (m) {
        int pre = __popcll(bal & ((1ULL << lane) - 1ULL));
        elist[base + pre] = (unsigned int)idx;
    }
}

// ---------------- edge bias MLP at true edges ----------------
// grid (4096, 3) x 256 : thread per (edge, layer)
__global__ __launch_bounds__(256) void k_edge_bias(
    const float* __restrict__ ef, const unsigned int* __restrict__ counter,
    const unsigned int* __restrict__ elist,
    const float* __restrict__ epw, const float* __restrict__ epb,
    const float* __restrict__ eb1w, const float* __restrict__ eb1b,
    const float* __restrict__ lng, const float* __restrict__ lnb,
    const float* __restrict__ eb2w, const float* __restrict__ eb2b,
    float* __restrict__ bias) {
    unsigned int count = *counter;
    unsigned int idx = blockIdx.x * 256 + threadIdx.x;
    if (idx >= count) return;
    int l = blockIdx.y;
    unsigned int pos = elist[idx];      // b*N*N + i*N + j
    int b = pos >> 18; int ij = pos & (NNSQ - 1);
    const float* e7 = ef + (size_t)pos * 7;
    float f0 = e7[0], f1 = e7[1], f2 = e7[2], f3 = e7[3], f4 = e7[4], f5 = e7[5], f6 = e7[6];
    float tt[16];
#pragma unroll
    for (int c = 0; c < 16; c++) tt[c] = eb1b[l * 16 + c];
    const float* W1 = eb1w + l * 1024;
    for (int k = 0; k < 64; k++) {
        float ek = epb[k] + f0 * epw[k] + f1 * epw[64 + k] + f2 * epw[128 + k] + f3 * epw[192 + k]
                 + f4 * epw[256 + k] + f5 * epw[320 + k] + f6 * epw[384 + k];
#pragma unroll
        for (int c = 0; c < 16; c++) tt[c] += ek * W1[k * 16 + c];
    }
    float m = 0.f;
#pragma unroll
    for (int c = 0; c < 16; c++) m += tt[c];
    m *= 0.0625f;
    float var = 0.f;
#pragma unroll
    for (int c = 0; c < 16; c++) { float d = tt[c] - m; var += d * d; }
    var *= 0.0625f;
    float inv = rsqrtf(var + 1e-5f);
#pragma unroll
    for (int c = 0; c < 16; c++) {
        float x = (tt[c] - m) * inv * lng[l * 16 + c] + lnb[l * 16 + c];
        tt[c] = x >= 0.f ? x : 0.2f * x;
    }
#pragma unroll
    for (int hh = 0; hh < 4; hh++) {
        float a = eb2b[l * 4 + hh];
#pragma unroll
        for (int c = 0; c < 16; c++) a += tt[c] * eb2w[(l * 16 + c) * 4 + hh];
        bias[(size_t)((l * 4 + b) * 4 + hh) * NNSQ + ij] = a;
    }
}

// ---------------- node projection ----------------
// grid 512 x 256 : wave per row
__global__ void k_node_proj(const float* __restrict__ nf, const float* __restrict__ w,
                            const float* __restrict__ bb, float* __restrict__ h) {
    int wid = blockIdx.x * 4 + (threadIdx.x >> 6);
    int f = threadIdx.x & 63;
    const float* r = nf + (size_t)wid * 18;
    float acc = bb[f];
#pragma unroll
    for (int c = 0; c < 18; c++) acc += r[c] * w[c * 64 + f];
    h[(size_t)wid * 64 + f] = acc;
}

// ---------------- QKV projection; K,V written head-transposed ----------------
// Q: [b*512+row][64]   KT/VT: [(b*64 + hh*16 + d)][512]  (i.e. [bh][d][j])
// grid 128 x 256 : block handles 16 rows, wave handles 4 rows
__global__ __launch_bounds__(256) void k_qkvT(
    const float* __restrict__ h,
    const float* __restrict__ WQ, const float* __restrict__ WK, const float* __restrict__ WV,
    float* __restrict__ Q, float* __restrict__ KT, float* __restrict__ VT) {
    __shared__ float h_lds[16][64];
    int t = threadIdx.x;
    size_t base = (size_t)blockIdx.x * 16 * 64;
    for (int u = t; u < 1024; u += 256) ((float*)h_lds)[u] = h[base + u];
    __syncthreads();
    int wv = t >> 6, lane = t & 63;
    float aq[4] = {0,0,0,0}, ak[4] = {0,0,0,0}, av[4] = {0,0,0,0};
    for (int k = 0; k < 64; k++) {
        float wqv = WQ[k * 64 + lane], wkv = WK[k * 64 + lane], wvv = WV[k * 64 + lane];
#pragma unroll
        for (int r = 0; r < 4; r++) {
            float hv = h_lds[wv * 4 + r][k];
            aq[r] += hv * wqv; ak[r] += hv * wkv; av[r] += hv * wvv;
        }
    }
#pragma unroll
    for (int r = 0; r < 4; r++) {
        Q[base + (size_t)(wv * 4 + r) * 64 + lane] = aq[r];
    }
    int b = blockIdx.x >> 5;                       // row block 512 rows per batch
    int j0 = (blockIdx.x & 31) * 16 + wv * 4;      // j within batch, multiple of 4
    float4 kk; kk.x = ak[0]; kk.y = ak[1]; kk.z = ak[2]; kk.w = ak[3];
    float4 vv; vv.x = av[0]; vv.y = av[1]; vv.z = av[2]; vv.w = av[3];
    *(float4*)(KT + ((size_t)(b * 64 + lane)) * 512 + j0) = kk;
    *(float4*)(VT + ((size_t)(b * 64 + lane)) * 512 + j0) = vv;
}

// ---------------- attention v2: block per (bh, 16-row tile) ----------------
// LDS-staged KT/VT (conflict-free b32 reads), Q in regs, P in regs.
// grid (16, 32) x 256
__global__ __launch_bounds__(256) void k_attn2(
    const float* __restrict__ Q, const float* __restrict__ KT, const float* __restrict__ VT,
    const float* __restrict__ biasL, const int* __restrict__ nmask,
    float* __restrict__ attO) {
    __shared__ float kt[8192];   // 32 KB  (reused as reduction scratch at the end)
    __shared__ float vt[8192];   // 32 KB
    int bh = blockIdx.x;         // b*4+hh
    int b  = bh >> 2;
    int i0 = blockIdx.y * 16;
    int t = threadIdx.x;
    const float4* ktg = (const float4*)(KT + (size_t)bh * 8192);
    const float4* vtg = (const float4*)(VT + (size_t)bh * 8192);
    float4* kts = (float4*)kt; float4* vts = (float4*)vt;
#pragma unroll
    for (int u = 0; u < 8; u++) {
        kts[t + u * 256] = ktg[t + u * 256];
        vts[t + u * 256] = vtg[t + u * 256];
    }
    int wv = t >> 6, lane = t & 63;
    int rbase = i0 + wv * 4;     // this wave's 4 query rows
    // fetch Q tile (4 rows x 16 dims) coalesced, broadcast into per-lane regs
    float qv = Q[((size_t)(b * 512 + rbase + (lane >> 4))) * 64 + (bh & 3) * 16 + (lane & 15)];
    float q[4][16];
#pragma unroll
    for (int r = 0; r < 4; r++)
#pragma unroll
        for (int d = 0; d < 16; d++)
            q[r][d] = __shfl(qv, r * 16 + d);
    __syncthreads();
    const float* brow = biasL + (size_t)bh * NNSQ + (size_t)rbase * 512;
    const int* nmb = nmask + b * 512;
    float sc[8][4];
    float mx[4] = {-3e38f, -3e38f, -3e38f, -3e38f};
#pragma unroll
    for (int c = 0; c < 8; c++) {
        int j = c * 64 + lane;
        float ktv[16];
#pragma unroll
        for (int d = 0; d < 16; d++) ktv[d] = kt[d * 512 + j];   // lane-coalesced, no conflicts
        float madd = (nmb[j] != 0) ? 0.f : -1e9f;
        float b0 = brow[j], b1 = brow[512 + j], b2 = brow[1024 + j], b3 = brow[1536 + j];
        float bz[4] = {b0, b1, b2, b3};
#pragma unroll
        for (int r = 0; r < 4; r++) {
            float s = 0.f;
#pragma unroll
            for (int d = 0; d < 16; d++) s += q[r][d] * ktv[d];
            s = s * 0.25f + bz[r] + madd;
            sc[c][r] = s;
            mx[r] = fmaxf(mx[r], s);
        }
    }
#pragma unroll
    for (int r = 0; r < 4; r++) mx[r] = wmaxr(mx[r]);
    float sm[4] = {0.f, 0.f, 0.f, 0.f};
#pragma unroll
    for (int c = 0; c < 8; c++)
#pragma unroll
        for (int r = 0; r < 4; r++) { sc[c][r] = __expf(sc[c][r] - mx[r]); sm[r] += sc[c][r]; }
#pragma unroll
    for (int r = 0; r < 4; r++) sm[r] = 1.0f / wsum(sm[r]);
#pragma unroll
    for (int c = 0; c < 8; c++)
#pragma unroll
        for (int r = 0; r < 4; r++) sc[c][r] *= sm[r];
    // PV: per-lane partials over this lane's 8 j values
    float acc[4][16];
#pragma unroll
    for (int r = 0; r < 4; r++)
#pragma unroll
        for (int d = 0; d < 16; d++) acc[r][d] = 0.f;
#pragma unroll
    for (int c = 0; c < 8; c++) {
        int j = c * 64 + lane;
#pragma unroll
        for (int d = 0; d < 16; d++) {
            float v = vt[d * 512 + j];                            // lane-coalesced, no conflicts
#pragma unroll
            for (int r = 0; r < 4; r++) acc[r][d] += sc[c][r] * v;
        }
    }
    // reduce over j: fold lane groups {L, L^16, L^32, L^48}
#pragma unroll
    for (int r = 0; r < 4; r++)
#pragma unroll
        for (int d = 0; d < 16; d++) {
            acc[r][d] += __shfl_xor(acc[r][d], 16);
            acc[r][d] += __shfl_xor(acc[r][d], 32);
        }
    __syncthreads();              // all waves done reading kt -> reuse as scratch
    float* scr = kt + wv * 1040;  // 16 lanes x 65-stride (conflict-free both directions)
    if (lane < 16) {
#pragma unroll
        for (int r = 0; r < 4; r++)
#pragma unroll
            for (int d = 0; d < 16; d++) scr[lane * 65 + r * 16 + d] = acc[r][d];
    }
    float o = 0.f;
#pragma unroll
    for (int m = 0; m < 16; m++) o += scr[m * 65 + lane];
    // lane encodes (r = lane>>4, d = lane&15)
    attO[((size_t)(b * 512 + rbase + (lane >> 4))) * 64 + (bh & 3) * 16 + (lane & 15)] = o;
}

// ---------------- output projection + residual + LN1 (in-place h) ----------------
// grid 512 x 256 : wave per row
__global__ __launch_bounds__(256) void k_oproj_ln1(
    const float* __restrict__ attO, const float* __restrict__ W, const float* __restrict__ Wb,
    const float* __restrict__ G, const float* __restrict__ Bt,
    float* __restrict__ h) {
    __shared__ float a_lds[4][64];
    int wv = threadIdx.x >> 6, lane = threadIdx.x & 63;
    int row = blockIdx.x * 4 + wv;
    a_lds[wv][lane] = attO[(size_t)row * 64 + lane];
    __syncthreads();
    float acc = Wb[lane];
#pragma unroll 8
    for (int k = 0; k < 64; k++) acc += a_lds[wv][k] * W[k * 64 + lane];
    float x = acc + h[(size_t)row * 64 + lane];
    float mn = wsum(x) * 0.015625f;
    float d = x - mn;
    float var = wsum(d * d) * 0.015625f;
    h[(size_t)row * 64 + lane] = d * rsqrtf(var + 1e-5f) * G[lane] + Bt[lane];
}

// ---------------- FFN + residual + LN2 (in-place h) ----------------
// grid 128 x 256 : block 16 rows, wave 4 rows
__global__ __launch_bounds__(256) void k_ffn(
    const float* __restrict__ W1, const float* __restrict__ B1,
    const float* __restrict__ W2, const float* __restrict__ B2,
    const float* __restrict__ G, const float* __restrict__ Bt,
    float* __restrict__ h) {
    __shared__ float h_lds[16][64];
    __shared__ float ff_lds[16][256];
    int t = threadIdx.x;
    size_t base = (size_t)blockIdx.x * 16 * 64;
    for (int u = t; u < 1024; u += 256) ((float*)h_lds)[u] = h[base + u];
    __syncthreads();
    int wv = t >> 6, lane = t & 63;
    float acc[4][4];
#pragma unroll
    for (int m = 0; m < 4; m++) {
        float bv = B1[m * 64 + lane];
#pragma unroll
        for (int r = 0; r < 4; r++) acc[m][r] = bv;
    }
    for (int k = 0; k < 64; k++) {
        float w0 = W1[k * 256 + lane], w1 = W1[k * 256 + 64 + lane],
              w2 = W1[k * 256 + 128 + lane], w3 = W1[k * 256 + 192 + lane];
#pragma unroll
        for (int r = 0; r < 4; r++) {
            float hv = h_lds[wv * 4 + r][k];
            acc[0][r] += hv * w0; acc[1][r] += hv * w1;
            acc[2][r] += hv * w2; acc[3][r] += hv * w3;
        }
    }
#pragma unroll
    for (int m = 0; m < 4; m++)
#pragma unroll
        for (int r = 0; r < 4; r++) {
            float u = acc[m][r];
            ff_lds[wv * 4 + r][m * 64 + lane] = 0.5f * u * (1.0f + erff(u * 0.70710678118654752f));
        }
    __syncthreads();
    float a2[4] = {0,0,0,0};
    for (int k = 0; k < 256; k++) {
        float w = W2[k * 64 + lane];
#pragma unroll
        for (int r = 0; r < 4; r++) a2[r] += ff_lds[wv * 4 + r][k] * w;
    }
    float b2v = B2[lane], gv = G[lane], btv = Bt[lane];
#pragma unroll
    for (int r = 0; r < 4; r++) {
        float x = a2[r] + b2v + h_lds[wv * 4 + r][lane];
        float mn = wsum(x) * 0.015625f;
        float d = x - mn;
        float var = wsum(d * d) * 0.015625f;
        h[base + (size_t)(wv * 4 + r) * 64 + lane] = d * rsqrtf(var + 1e-5f) * gv + btv;
    }
}

// ---------------- scoring head ----------------
// grid 511 x 256 : wave per candidate (b, j)
__global__ __launch_bounds__(256) void k_score(
    const float* __restrict__ h, const float* __restrict__ s1w, const float* __restrict__ s1b,
    const float* __restrict__ lng, const float* __restrict__ lnb,
    const float* __restrict__ s2w, const float* __restrict__ s2b,
    float* __restrict__ logits) {
    __shared__ float c_lds[4][128];
    int wv = threadIdx.x >> 6, lane = threadIdx.x & 63;
    int wid = blockIdx.x * 4 + wv;      // 0..2043
    int b = wid / 511; int jj = wid % 511; int j = jj + 1;
    c_lds[wv][lane]      = h[((size_t)b * 512) * 64 + lane];
    c_lds[wv][64 + lane] = h[((size_t)(b * 512 + j)) * 64 + lane];
    __syncthreads();
    float acc = s1b[lane];
#pragma unroll 8
    for (int k = 0; k < 128; k++) acc += c_lds[wv][k] * s1w[k * 64 + lane];
    float mn = wsum(acc) * 0.015625f;
    float d = acc - mn;
    float var = wsum(d * d) * 0.015625f;
    float x = d * rsqrtf(var + 1e-5f) * lng[lane] + lnb[lane];
    x = x >= 0.f ? x : 0.2f * x;
    float p = wsum(x * s2w[lane]);
    if (lane == 0) logits[wid] = p + s2b[0];
}

// ---------------- final softmax over candidates ----------------
// grid 4 x 512
__global__ __launch_bounds__(512) void k_probs(
    const float* __restrict__ logits, const int* __restrict__ nmask, float* __restrict__ out) {
    __shared__ float red[512];
    __shared__ int anyf;
    int b = blockIdx.x; int t = threadIdx.x;
    bool cand = false;
    if (t < 511) cand = nmask[b * 512 + 1 + t] != 0;
    if (t == 0) anyf = 0;
    __syncthreads();
    if (cand) atomicOr(&anyf, 1);
    __syncthreads();
    if (t == 0 && anyf == 0) cand = true;
    float val = -3e38f;
    if (t < 511) val = cand ? logits[b * 511 + t] : -1e9f;
    red[t] = val; __syncthreads();
    for (int s = 256; s > 0; s >>= 1) { if (t < s) red[t] = fmaxf(red[t], red[t + s]); __syncthreads(); }
    float m = red[0]; __syncthreads();
    float p = (t < 511) ? __expf(val - m) : 0.f;
    red[t] = p; __syncthreads();
    for (int s = 256; s > 0; s >>= 1) { if (t < s) red[t] += red[t + s]; __syncthreads(); }
    float inv = 1.0f / red[0];
    if (t < 511) out[b * 511 + t] = p * inv;
}

// ---------------- copy final h to output ----------------
__global__ void k_copy_h(const float4* __restrict__ src, float4* __restrict__ dst) {
    int i = blockIdx.x * 256 + threadIdx.x;   // 32768 float4
    dst[i] = src[i];
}

extern "C" void kernel_launch(void* const* d_in, const int* in_sizes, int n_in,
                              void* d_out, int out_size, void* d_ws, size_t ws_size,
                              hipStream_t stream) {
    const float* nf    = (const float*)d_in[0];
    const float* ef    = (const float*)d_in[1];
    const int*   nm    = (const int*)d_in[2];
    const int*   em    = (const int*)d_in[3];
    const float* npw   = (const float*)d_in[4];
    const float* npb   = (const float*)d_in[5];
    const float* epw   = (const float*)d_in[6];
    const float* epb   = (const float*)d_in[7];
    const float* wq    = (const float*)d_in[8];
    const float* wk    = (const float*)d_in[9];
    const float* wv    = (const float*)d_in[10];
    const float* eb1w  = (const float*)d_in[11];
    const float* eb1b  = (const float*)d_in[12];
    const float* eblng = (const float*)d_in[13];
    const float* eblnb = (const float*)d_in[14];
    const float* eb2w  = (const float*)d_in[15];
    const float* eb2b  = (const float*)d_in[16];
    const float* s1wv  = (const float*)d_in[17];  // spd1_w
    const float* s1bv  = (const float*)d_in[18];
    const float* s2wv  = (const float*)d_in[19];
    const float* s2bv  = (const float*)d_in[20];
    const float* wow   = (const float*)d_in[21];
    const float* wob   = (const float*)d_in[22];
    const float* ln1g  = (const float*)d_in[23];
    const float* ln1b  = (const float*)d_in[24];
    const float* ln2g  = (const float*)d_in[25];
    const float* ln2b  = (const float*)d_in[26];
    const float* f1w   = (const float*)d_in[27];
    const float* f1b   = (const float*)d_in[28];
    const float* f2w   = (const float*)d_in[29];
    const float* f2b   = (const float*)d_in[30];
    const float* sc1w  = (const float*)d_in[31];
    const float* sc1b  = (const float*)d_in[32];
    const float* sclng = (const float*)d_in[33];
    const float* sclnb = (const float*)d_in[34];
    const float* sc2w  = (const float*)d_in[35];
    const float* sc2b  = (const float*)d_in[36];

    char* W = (char*)d_ws;
    float*              bias    = (float*)(W + 0);                 // 50,331,648 B
    unsigned long long* adj     = (unsigned long long*)(W + 50331648); // 131,072 B
    unsigned char*      spd     = (unsigned char*)(W + 50462720);  // 1,048,576 B
    float*              table   = (float*)(W + 51511296);          // 1,024 B
    unsigned int*       counter = (unsigned int*)(W + 51512320);   // 256 B
    unsigned int*       elist   = (unsigned int*)(W + 51512576);   // 4,194,304 B
    float*              hbuf    = (float*)(W + 55706880);          // 524,288 B
    float*              Qb      = (float*)(W + 56231168);
    float*              KTb     = (float*)(W + 56755456);          // [4][64][512]
    float*              VTb     = (float*)(W + 57279744);          // [4][64][512]
    float*              attO    = (float*)(W + 57804032);
    float*              logits  = (float*)(W + 58328320);          // 8,176 B
    unsigned int*       blockCnt= (unsigned int*)(W + 58337280);   // 16,384 B
    unsigned int*       blockOff= (unsigned int*)(W + 58353664);   // 16,384 B

    float* out = (float*)d_out;                 // [probs 2044][h 131072]

    k_adj<<<4096, 256, 0, stream>>>(em, adj);
    k_spd_table<<<1, 256, 0, stream>>>(s1wv, s1bv, s2wv, s2bv, table);
    k_bfs<<<2048, 64, 0, stream>>>(adj, spd);
    k_fill_bias<<<4096, 256, 0, stream>>>(spd, table, bias);
    k_count<<<4096, 256, 0, stream>>>(em, blockCnt);
    k_scan<<<1, 1024, 0, stream>>>(blockCnt, blockOff, counter);
    k_scatter<<<4096, 256, 0, stream>>>(em, blockOff, elist);
    k_edge_bias<<<dim3(4096, 3), 256, 0, stream>>>(ef, counter, elist, epw, epb,
                                                   eb1w, eb1b, eblng, eblnb, eb2w, eb2b, bias);
    k_node_proj<<<512, 256, 0, stream>>>(nf, npw, npb, hbuf);

    for (int l = 0; l < LL; l++) {
        k_qkvT<<<128, 256, 0, stream>>>(hbuf, wq + l * 4096, wk + l * 4096, wv + l * 4096,
                                        Qb, KTb, VTb);
        k_attn2<<<dim3(16, 32), 256, 0, stream>>>(Qb, KTb, VTb,
                                                  bias + (size_t)l * 16 * NNSQ, nm, attO);
        k_oproj_ln1<<<512, 256, 0, stream>>>(attO, wow + l * 4096, wob + l * 64,
                                             ln1g + l * 64, ln1b + l * 64, hbuf);
        k_ffn<<<128, 256, 0, stream>>>(f1w + l * 16384, f1b + l * 256,
                                       f2w + l * 16384, f2b + l * 64,
                                       ln2g + l * 64, ln2b + l * 64, hbuf);
    }

    k_score<<<511, 256, 0, stream>>>(hbuf, sc1w, sc1b, sclng, sclnb, sc2w, sc2b, logits);
    k_copy_h<<<128, 256, 0, stream>>>((const float4*)hbuf, (float4*)(out + 2044));
    k_probs<<<4, 512, 0, stream>>>(logits, nm, out);
}

// Round 4
// 348.355 us; speedup vs baseline: 1.8104x; 1.0333x over previous
//
#include <hip/hip_runtime.h>
#include <math.h>

// Problem constants
#define BB 4
#define NN 512
#define HH 64
#define NHH 4
#define HDD 16
#define LL 3
#define NNSQ 262144          // N*N
#define FFF 256

// ---------------- wave helpers ----------------
__device__ __forceinline__ float wsum(float x) {
#pragma unroll
    for (int o = 1; o < 64; o <<= 1) x += __shfl_xor(x, o);
    return x;
}
__device__ __forceinline__ float wmaxr(float x) {
#pragma unroll
    for (int o = 1; o < 64; o <<= 1) x = fmaxf(x, __shfl_xor(x, o));
    return x;
}

// ---------------- adjacency bitsets + per-256-chunk edge counts (fused) ----------------
// grid 4096 x 256 : wave per (row, 64-col chunk); block covers em idx [256*blk, 256*blk+256)
__global__ void k_adj(const int* __restrict__ em, unsigned long long* __restrict__ adj,
                      unsigned int* __restrict__ blockCnt) {
    __shared__ unsigned int wc[4];
    int wv = threadIdx.x >> 6, lane = threadIdx.x & 63;
    int wid = blockIdx.x * 4 + wv;
    int chunk = wid & 7;
    int row = wid >> 3;                 // b*N + i
    int j = chunk * 64 + lane;
    int v = em[(size_t)row * NN + j];
    unsigned long long bal = __ballot(v != 0);
    if (lane == 0) { adj[row * 8 + chunk] = bal; wc[wv] = (unsigned int)__popcll(bal); }
    __syncthreads();
    if (threadIdx.x == 0) blockCnt[blockIdx.x] = wc[0] + wc[1] + wc[2] + wc[3];
}

// ---------------- BFS (levels 1..9, >=10 -> 10) ----------------
// grid 2048 x 64 : one wave per source row
__global__ void k_bfs(const unsigned long long* __restrict__ adj, unsigned char* __restrict__ spd) {
    __shared__ unsigned long long vis[8], fro[8], nxt[8];
    __shared__ unsigned long long dist8[64];
    unsigned char* dist = (unsigned char*)dist8;
    int t = threadIdx.x;
    int row = blockIdx.x;               // b*N + i
    int b = row >> 9; int src = row & 511;
    dist8[t] = 0x0A0A0A0A0A0A0A0AULL;   // init all to 10
    if (t < 8) { vis[t] = 0ULL; fro[t] = 0ULL; }
    __syncthreads();
    if (t == 0) {
        dist[src] = 0;
        vis[src >> 6] = 1ULL << (src & 63);
        fro[src >> 6] = 1ULL << (src & 63);
    }
    __syncthreads();
    const unsigned long long* arow = adj + (size_t)b * NN * 8;
    for (int d = 1; d <= 9; d++) {
        if (t < 8) nxt[t] = 0ULL;
        __syncthreads();
        int c = t >> 3, w = t & 7;
        unsigned long long f = fro[c];
        unsigned long long acc = 0ULL;
        while (f) {
            int k = (c << 6) + __builtin_ctzll(f);
            f &= f - 1;
            acc |= arow[k * 8 + w];
        }
        if (acc) atomicOr(&nxt[w], acc);
        __syncthreads();
        if (t < 8) {
            unsigned long long nw = nxt[t] & ~vis[t];
            vis[t] |= nw;
            fro[t] = nw;
            while (nw) {
                int j = (t << 6) + __builtin_ctzll(nw);
                nw &= nw - 1;
                dist[j] = (unsigned char)d;
            }
        }
        __syncthreads();
    }
    ((unsigned long long*)(spd + (size_t)row * NN))[t] = dist8[t];
}

// ---------------- scan: exclusive prefix over 4096 chunk counts (+ total sentinel) ----------------
// 1 block x 1024
__global__ __launch_bounds__(1024) void k_scan(const unsigned int* __restrict__ blockCnt,
                                               unsigned int* __restrict__ blockOff,
                                               unsigned int* __restrict__ counter) {
    __shared__ unsigned int part[1024];
    int t = threadIdx.x;
    unsigned int v0 = blockCnt[t * 4], v1 = blockCnt[t * 4 + 1],
                 v2 = blockCnt[t * 4 + 2], v3 = blockCnt[t * 4 + 3];
    unsigned int s = v0 + v1 + v2 + v3;
    part[t] = s;
    __syncthreads();
    for (int o = 1; o < 1024; o <<= 1) {
        unsigned int add = (t >= o) ? part[t - o] : 0u;
        __syncthreads();
        part[t] += add;
        __syncthreads();
    }
    unsigned int excl = part[t] - s;
    blockOff[t * 4]     = excl;
    blockOff[t * 4 + 1] = excl + v0;
    blockOff[t * 4 + 2] = excl + v0 + v1;
    blockOff[t * 4 + 3] = excl + v0 + v1 + v2;
    if (t == 1023) { counter[0] = part[t]; blockOff[4096] = part[t]; }
}

// ---------------- scatter edge indices (globally sorted -> CSR-compatible) ----------------
// grid 4096 x 256
__global__ void k_scatter(const int* __restrict__ em, const unsigned int* __restrict__ blockOff,
                          unsigned int* __restrict__ elist) {
    __shared__ unsigned int wc[4];
    int t = threadIdx.x; int lane = t & 63; int wv = t >> 6;
    int idx = blockIdx.x * 256 + t;
    bool m = em[idx] != 0;
    unsigned long long bal = __ballot(m);
    if (lane == 0) wc[wv] = (unsigned int)__popcll(bal);
    __syncthreads();
    unsigned int base = blockOff[blockIdx.x];
    for (int w = 0; w < wv; w++) base += wc[w];
    if (m) {
        int pre = __popcll(bal & ((1ULL << lane) - 1ULL));
        elist[base + pre] = (unsigned int)idx;
    }
}

// ---------------- edge bias MLP -> compact planes vals[(l*4+h)<<16 | e] ----------------
// grid (256, 3) x 256 : thread per (edge, layer); covers up to 65536 edges
__global__ __launch_bounds__(256) void k_edge_bias(
    const float* __restrict__ ef, const unsigned int* __restrict__ counter,
    const unsigned int* __restrict__ elist,
    const float* __restrict__ epw, const float* __restrict__ epb,
    const float* __restrict__ eb1w, const float* __restrict__ eb1b,
    const float* __restrict__ lng, const float* __restrict__ lnb,
    const float* __restrict__ eb2w, const float* __restrict__ eb2b,
    float* __restrict__ vals) {
    unsigned int count = *counter;
    unsigned int idx = blockIdx.x * 256 + threadIdx.x;
    if (idx >= count) return;
    int l = blockIdx.y;
    unsigned int pos = elist[idx];      // (b*N+i)*N + j
    const float* e7 = ef + (size_t)pos * 7;
    float f0 = e7[0], f1 = e7[1], f2 = e7[2], f3 = e7[3], f4 = e7[4], f5 = e7[5], f6 = e7[6];
    float tt[16];
#pragma unroll
    for (int c = 0; c < 16; c++) tt[c] = eb1b[l * 16 + c];
    const float* W1 = eb1w + l * 1024;
    for (int k = 0; k < 64; k++) {
        float ek = epb[k] + f0 * epw[k] + f1 * epw[64 + k] + f2 * epw[128 + k] + f3 * epw[192 + k]
                 + f4 * epw[256 + k] + f5 * epw[320 + k] + f6 * epw[384 + k];
#pragma unroll
        for (int c = 0; c < 16; c++) tt[c] += ek * W1[k * 16 + c];
    }
    float m = 0.f;
#pragma unroll
    for (int c = 0; c < 16; c++) m += tt[c];
    m *= 0.0625f;
    float var = 0.f;
#pragma unroll
    for (int c = 0; c < 16; c++) { float d = tt[c] - m; var += d * d; }
    var *= 0.0625f;
    float inv = rsqrtf(var + 1e-5f);
#pragma unroll
    for (int c = 0; c < 16; c++) {
        float x = (tt[c] - m) * inv * lng[l * 16 + c] + lnb[l * 16 + c];
        tt[c] = x >= 0.f ? x : 0.2f * x;
    }
#pragma unroll
    for (int hh = 0; hh < 4; hh++) {
        float a = eb2b[l * 4 + hh];
#pragma unroll
        for (int c = 0; c < 16; c++) a += tt[c] * eb2w[(l * 16 + c) * 4 + hh];
        vals[(unsigned int)((l * 4 + hh) << 16) + idx] = a;
    }
}

// ---------------- node projection ----------------
// grid 512 x 256 : wave per row
__global__ void k_node_proj(const float* __restrict__ nf, const float* __restrict__ w,
                            const float* __restrict__ bb, float* __restrict__ h) {
    int wid = blockIdx.x * 4 + (threadIdx.x >> 6);
    int f = threadIdx.x & 63;
    const float* r = nf + (size_t)wid * 18;
    float acc = bb[f];
#pragma unroll
    for (int c = 0; c < 18; c++) acc += r[c] * w[c * 64 + f];
    h[(size_t)wid * 64 + f] = acc;
}

// ---------------- QKV projection; K,V written head-transposed ----------------
// Q: [b*512+row][64]   KT/VT: [(b*64 + hh*16 + d)][512]  (i.e. [bh][d][j])
// grid 128 x 256 : block handles 16 rows, wave handles 4 rows
__global__ __launch_bounds__(256) void k_qkvT(
    const float* __restrict__ h,
    const float* __restrict__ WQ, const float* __restrict__ WK, const float* __restrict__ WV,
    float* __restrict__ Q, float* __restrict__ KT, float* __restrict__ VT) {
    __shared__ float h_lds[16][64];
    int t = threadIdx.x;
    size_t base = (size_t)blockIdx.x * 16 * 64;
    for (int u = t; u < 1024; u += 256) ((float*)h_lds)[u] = h[base + u];
    __syncthreads();
    int wv = t >> 6, lane = t & 63;
    float aq[4] = {0,0,0,0}, ak[4] = {0,0,0,0}, av[4] = {0,0,0,0};
    for (int k = 0; k < 64; k++) {
        float wqv = WQ[k * 64 + lane], wkv = WK[k * 64 + lane], wvv = WV[k * 64 + lane];
#pragma unroll
        for (int r = 0; r < 4; r++) {
            float hv = h_lds[wv * 4 + r][k];
            aq[r] += hv * wqv; ak[r] += hv * wkv; av[r] += hv * wvv;
        }
    }
#pragma unroll
    for (int r = 0; r < 4; r++) {
        Q[base + (size_t)(wv * 4 + r) * 64 + lane] = aq[r];
    }
    int b = blockIdx.x >> 5;
    int j0 = (blockIdx.x & 31) * 16 + wv * 4;
    float4 kk; kk.x = ak[0]; kk.y = ak[1]; kk.z = ak[2]; kk.w = ak[3];
    float4 vv; vv.x = av[0]; vv.y = av[1]; vv.z = av[2]; vv.w = av[3];
    *(float4*)(KT + ((size_t)(b * 64 + lane)) * 512 + j0) = kk;
    *(float4*)(VT + ((size_t)(b * 64 + lane)) * 512 + j0) = vv;
}

// ---------------- attention v3: bias built in LDS from spd table + sparse edge overlay ----------------
// grid (16, 32) x 256 : block per (bh, 16-row tile)
__global__ __launch_bounds__(256) void k_attn3(
    const float* __restrict__ Q, const float* __restrict__ KT, const float* __restrict__ VT,
    const unsigned char* __restrict__ spd, const unsigned int* __restrict__ elist,
    const unsigned int* __restrict__ rowOff, const float* __restrict__ vals,
    const float* __restrict__ s1w, const float* __restrict__ s1b,
    const float* __restrict__ s2w, const float* __restrict__ s2b,
    const int* __restrict__ nmask, int l, float* __restrict__ attO) {
    __shared__ float kt[8192];   // K tile; reused as reduction scratch at the very end
    __shared__ float bv[8192];   // bias tile during QK; V tile during PV
    __shared__ float tab[11];
    int bh = blockIdx.x;         // b*4+hh
    int b  = bh >> 2, hh = bh & 3;
    int i0 = blockIdx.y * 16;
    int t = threadIdx.x, wv = t >> 6, lane = t & 63;
    int rbase = i0 + wv * 4;
    // Q tile -> registers (wave-local broadcast)
    float qv = Q[((size_t)(b * 512 + rbase + (lane >> 4))) * 64 + hh * 16 + (lane & 15)];
    float q[4][16];
#pragma unroll
    for (int r = 0; r < 4; r++)
#pragma unroll
        for (int d = 0; d < 16; d++)
            q[r][d] = __shfl(qv, r * 16 + d);
    // stage K tile
    const float4* ktg = (const float4*)(KT + (size_t)bh * 8192);
    float4* kts = (float4*)kt;
#pragma unroll
    for (int u = 0; u < 8; u++) kts[t + u * 256] = ktg[t + u * 256];
    // spd bias table for this (l, hh): 11 entries
    if (t < 11) {
        float x = (float)t * 0.1f;
        float acc = s2b[l * 4 + hh];
#pragma unroll
        for (int c = 0; c < 16; c++) {
            float v = x * s1w[l * 16 + c] + s1b[l * 16 + c];
            v = v >= 0.f ? v : 0.2f * v;
            acc += v * s2w[(l * 16 + c) * 4 + hh];
        }
        tab[t] = acc;
    }
    __syncthreads();
    // bias tile init from spd bytes (rows i0..i0+15 contiguous within batch)
    const unsigned char* sp = spd + ((size_t)(b * 512 + i0)) * 512;
#pragma unroll
    for (int u = 0; u < 8; u++) {
        int e4 = u * 1024 + t * 4;
        unsigned int w4 = *(const unsigned int*)(sp + e4);
        bv[e4 + 0] = tab[w4 & 255u];
        bv[e4 + 1] = tab[(w4 >> 8) & 255u];
        bv[e4 + 2] = tab[(w4 >> 16) & 255u];
        bv[e4 + 3] = tab[w4 >> 24];
    }
    __syncthreads();
    // sparse edge overlay: row g's edges are elist[rowOff[2g] .. rowOff[2g+2])
    unsigned int vplane = (unsigned int)((l * 4 + hh) << 16);
#pragma unroll
    for (int rr = 0; rr < 4; rr++) {
        int g = b * 512 + rbase + rr;
        unsigned int e0 = rowOff[2 * g], e1 = rowOff[2 * g + 2];
        for (unsigned int e = e0 + lane; e < e1; e += 64) {
            int j = (int)(elist[e] & 511u);
            bv[(wv * 4 + rr) * 512 + j] = vals[vplane + e];
        }
    }
    __syncthreads();
    // QK + bias + mask
    const int* nmb = nmask + b * 512;
    float sc[8][4];
    float mx[4] = {-3e38f, -3e38f, -3e38f, -3e38f};
#pragma unroll
    for (int c = 0; c < 8; c++) {
        int j = c * 64 + lane;
        float ktv[16];
#pragma unroll
        for (int d = 0; d < 16; d++) ktv[d] = kt[d * 512 + j];
        float madd = (nmb[j] != 0) ? 0.f : -1e9f;
#pragma unroll
        for (int r = 0; r < 4; r++) {
            float s = 0.f;
#pragma unroll
            for (int d = 0; d < 16; d++) s += q[r][d] * ktv[d];
            s = s * 0.25f + bv[(wv * 4 + r) * 512 + j] + madd;
            sc[c][r] = s;
            mx[r] = fmaxf(mx[r], s);
        }
    }
#pragma unroll
    for (int r = 0; r < 4; r++) mx[r] = wmaxr(mx[r]);
    float sm[4] = {0.f, 0.f, 0.f, 0.f};
#pragma unroll
    for (int c = 0; c < 8; c++)
#pragma unroll
        for (int r = 0; r < 4; r++) { sc[c][r] = __expf(sc[c][r] - mx[r]); sm[r] += sc[c][r]; }
#pragma unroll
    for (int r = 0; r < 4; r++) sm[r] = 1.0f / wsum(sm[r]);
#pragma unroll
    for (int c = 0; c < 8; c++)
#pragma unroll
        for (int r = 0; r < 4; r++) sc[c][r] *= sm[r];
    __syncthreads();              // everyone done reading bv (bias)
    // stage V tile into bv
    const float4* vtg = (const float4*)(VT + (size_t)bh * 8192);
    float4* vts = (float4*)bv;
#pragma unroll
    for (int u = 0; u < 8; u++) vts[t + u * 256] = vtg[t + u * 256];
    __syncthreads();
    // PV: per-lane partials over this lane's 8 j values
    float acc[4][16];
#pragma unroll
    for (int r = 0; r < 4; r++)
#pragma unroll
        for (int d = 0; d < 16; d++) acc[r][d] = 0.f;
#pragma unroll
    for (int c = 0; c < 8; c++) {
        int j = c * 64 + lane;
#pragma unroll
        for (int d = 0; d < 16; d++) {
            float v = bv[d * 512 + j];
#pragma unroll
            for (int r = 0; r < 4; r++) acc[r][d] += sc[c][r] * v;
        }
    }
#pragma unroll
    for (int r = 0; r < 4; r++)
#pragma unroll
        for (int d = 0; d < 16; d++) {
            acc[r][d] += __shfl_xor(acc[r][d], 16);
            acc[r][d] += __shfl_xor(acc[r][d], 32);
        }
    __syncthreads();              // kt free -> reduction scratch
    float* scr = kt + wv * 1040;  // 16 x stride-65, conflict-free
    if (lane < 16) {
#pragma unroll
        for (int r = 0; r < 4; r++)
#pragma unroll
            for (int d = 0; d < 16; d++) scr[lane * 65 + r * 16 + d] = acc[r][d];
    }
    float o = 0.f;
#pragma unroll
    for (int m = 0; m < 16; m++) o += scr[m * 65 + lane];
    attO[((size_t)(b * 512 + rbase + (lane >> 4))) * 64 + hh * 16 + (lane & 15)] = o;
}

// ---------------- output projection + residual + LN1 (in-place h) ----------------
// grid 512 x 256 : wave per row
__global__ __launch_bounds__(256) void k_oproj_ln1(
    const float* __restrict__ attO, const float* __restrict__ W, const float* __restrict__ Wb,
    const float* __restrict__ G, const float* __restrict__ Bt,
    float* __restrict__ h) {
    __shared__ float a_lds[4][64];
    int wv = threadIdx.x >> 6, lane = threadIdx.x & 63;
    int row = blockIdx.x * 4 + wv;
    a_lds[wv][lane] = attO[(size_t)row * 64 + lane];
    __syncthreads();
    float acc = Wb[lane];
#pragma unroll 8
    for (int k = 0; k < 64; k++) acc += a_lds[wv][k] * W[k * 64 + lane];
    float x = acc + h[(size_t)row * 64 + lane];
    float mn = wsum(x) * 0.015625f;
    float d = x - mn;
    float var = wsum(d * d) * 0.015625f;
    h[(size_t)row * 64 + lane] = d * rsqrtf(var + 1e-5f) * G[lane] + Bt[lane];
}

// ---------------- FFN + residual + LN2 (in-place h) ----------------
// grid 128 x 256 : block 16 rows, wave 4 rows
__global__ __launch_bounds__(256) void k_ffn(
    const float* __restrict__ W1, const float* __restrict__ B1,
    const float* __restrict__ W2, const float* __restrict__ B2,
    const float* __restrict__ G, const float* __restrict__ Bt,
    float* __restrict__ h) {
    __shared__ float h_lds[16][64];
    __shared__ float ff_lds[16][256];
    int t = threadIdx.x;
    size_t base = (size_t)blockIdx.x * 16 * 64;
    for (int u = t; u < 1024; u += 256) ((float*)h_lds)[u] = h[base + u];
    __syncthreads();
    int wv = t >> 6, lane = t & 63;
    float acc[4][4];
#pragma unroll
    for (int m = 0; m < 4; m++) {
        float bvv = B1[m * 64 + lane];
#pragma unroll
        for (int r = 0; r < 4; r++) acc[m][r] = bvv;
    }
    for (int k = 0; k < 64; k++) {
        float w0 = W1[k * 256 + lane], w1 = W1[k * 256 + 64 + lane],
              w2 = W1[k * 256 + 128 + lane], w3 = W1[k * 256 + 192 + lane];
#pragma unroll
        for (int r = 0; r < 4; r++) {
            float hv = h_lds[wv * 4 + r][k];
            acc[0][r] += hv * w0; acc[1][r] += hv * w1;
            acc[2][r] += hv * w2; acc[3][r] += hv * w3;
        }
    }
#pragma unroll
    for (int m = 0; m < 4; m++)
#pragma unroll
        for (int r = 0; r < 4; r++) {
            float u = acc[m][r];
            ff_lds[wv * 4 + r][m * 64 + lane] = 0.5f * u * (1.0f + erff(u * 0.70710678118654752f));
        }
    __syncthreads();
    float a2[4] = {0,0,0,0};
    for (int k = 0; k < 256; k++) {
        float w = W2[k * 64 + lane];
#pragma unroll
        for (int r = 0; r < 4; r++) a2[r] += ff_lds[wv * 4 + r][k] * w;
    }
    float b2v = B2[lane], gv = G[lane], btv = Bt[lane];
#pragma unroll
    for (int r = 0; r < 4; r++) {
        float x = a2[r] + b2v + h_lds[wv * 4 + r][lane];
        float mn = wsum(x) * 0.015625f;
        float d = x - mn;
        float var = wsum(d * d) * 0.015625f;
        h[base + (size_t)(wv * 4 + r) * 64 + lane] = d * rsqrtf(var + 1e-5f) * gv + btv;
    }
}

// ---------------- scoring head ----------------
// grid 511 x 256 : wave per candidate (b, j)
__global__ __launch_bounds__(256) void k_score(
    const float* __restrict__ h, const float* __restrict__ s1w, const float* __restrict__ s1b,
    const float* __restrict__ lng, const float* __restrict__ lnb,
    const float* __restrict__ s2w, const float* __restrict__ s2b,
    float* __restrict__ logits) {
    __shared__ float c_lds[4][128];
    int wv = threadIdx.x >> 6, lane = threadIdx.x & 63;
    int wid = blockIdx.x * 4 + wv;      // 0..2043
    int b = wid / 511; int jj = wid % 511; int j = jj + 1;
    c_lds[wv][lane]      = h[((size_t)b * 512) * 64 + lane];
    c_lds[wv][64 + lane] = h[((size_t)(b * 512 + j)) * 64 + lane];
    __syncthreads();
    float acc = s1b[lane];
#pragma unroll 8
    for (int k = 0; k < 128; k++) acc += c_lds[wv][k] * s1w[k * 64 + lane];
    float mn = wsum(acc) * 0.015625f;
    float d = acc - mn;
    float var = wsum(d * d) * 0.015625f;
    float x = d * rsqrtf(var + 1e-5f) * lng[lane] + lnb[lane];
    x = x >= 0.f ? x : 0.2f * x;
    float p = wsum(x * s2w[lane]);
    if (lane == 0) logits[wid] = p + s2b[0];
}

// ---------------- final softmax over candidates ----------------
// grid 4 x 512
__global__ __launch_bounds__(512) void k_probs(
    const float* __restrict__ logits, const int* __restrict__ nmask, float* __restrict__ out) {
    __shared__ float red[512];
    __shared__ int anyf;
    int b = blockIdx.x; int t = threadIdx.x;
    bool cand = false;
    if (t < 511) cand = nmask[b * 512 + 1 + t] != 0;
    if (t == 0) anyf = 0;
    __syncthreads();
    if (cand) atomicOr(&anyf, 1);
    __syncthreads();
    if (t == 0 && anyf == 0) cand = true;
    float val = -3e38f;
    if (t < 511) val = cand ? logits[b * 511 + t] : -1e9f;
    red[t] = val; __syncthreads();
    for (int s = 256; s > 0; s >>= 1) { if (t < s) red[t] = fmaxf(red[t], red[t + s]); __syncthreads(); }
    float m = red[0]; __syncthreads();
    float p = (t < 511) ? __expf(val - m) : 0.f;
    red[t] = p; __syncthreads();
    for (int s = 256; s > 0; s >>= 1) { if (t < s) red[t] += red[t + s]; __syncthreads(); }
    float inv = 1.0f / red[0];
    if (t < 511) out[b * 511 + t] = p * inv;
}

// ---------------- copy final h to output ----------------
__global__ void k_copy_h(const float4* __restrict__ src, float4* __restrict__ dst) {
    int i = blockIdx.x * 256 + threadIdx.x;   // 32768 float4
    dst[i] = src[i];
}

extern "C" void kernel_launch(void* const* d_in, const int* in_sizes, int n_in,
                              void* d_out, int out_size, void* d_ws, size_t ws_size,
                              hipStream_t stream) {
    const float* nf    = (const float*)d_in[0];
    const float* ef    = (const float*)d_in[1];
    const int*   nm    = (const int*)d_in[2];
    const int*   em    = (const int*)d_in[3];
    const float* npw   = (const float*)d_in[4];
    const float* npb   = (const float*)d_in[5];
    const float* epw   = (const float*)d_in[6];
    const float* epb   = (const float*)d_in[7];
    const float* wq    = (const float*)d_in[8];
    const float* wk    = (const float*)d_in[9];
    const float* wv    = (const float*)d_in[10];
    const float* eb1w  = (const float*)d_in[11];
    const float* eb1b  = (const float*)d_in[12];
    const float* eblng = (const float*)d_in[13];
    const float* eblnb = (const float*)d_in[14];
    const float* eb2w  = (const float*)d_in[15];
    const float* eb2b  = (const float*)d_in[16];
    const float* s1wv  = (const float*)d_in[17];  // spd1_w
    const float* s1bv  = (const float*)d_in[18];
    const float* s2wv  = (const float*)d_in[19];
    const float* s2bv  = (const float*)d_in[20];
    const float* wow   = (const float*)d_in[21];
    const float* wob   = (const float*)d_in[22];
    const float* ln1g  = (const float*)d_in[23];
    const float* ln1b  = (const float*)d_in[24];
    const float* ln2g  = (const float*)d_in[25];
    const float* ln2b  = (const float*)d_in[26];
    const float* f1w   = (const float*)d_in[27];
    const float* f1b   = (const float*)d_in[28];
    const float* f2w   = (const float*)d_in[29];
    const float* f2b   = (const float*)d_in[30];
    const float* sc1w  = (const float*)d_in[31];
    const float* sc1b  = (const float*)d_in[32];
    const float* sclng = (const float*)d_in[33];
    const float* sclnb = (const float*)d_in[34];
    const float* sc2w  = (const float*)d_in[35];
    const float* sc2b  = (const float*)d_in[36];

    char* W = (char*)d_ws;
    unsigned long long* adj     = (unsigned long long*)(W + 0);        // 131,072 B
    unsigned char*      spd     = (unsigned char*)(W + 131072);        // 1,048,576 B
    unsigned int*       counter = (unsigned int*)(W + 1179648);        // 256 B
    unsigned int*       elist   = (unsigned int*)(W + 1179904);        // 4,194,304 B
    float*              vals    = (float*)(W + 5374208);               // 3,145,728 B [12][65536]
    float*              hbuf    = (float*)(W + 8519936);               // 524,288 B
    float*              Qb      = (float*)(W + 9044224);               // 524,288 B
    float*              KTb     = (float*)(W + 9568512);               // 524,288 B  [4][64][512]
    float*              VTb     = (float*)(W + 10092800);              // 524,288 B
    float*              attO    = (float*)(W + 10617088);              // 524,288 B
    float*              logits  = (float*)(W + 11141376);              // 8,192 B
    unsigned int*       blockCnt= (unsigned int*)(W + 11149568);       // 16,384 B
    unsigned int*       blockOff= (unsigned int*)(W + 11165952);       // 16,388 B (4097 entries)

    float* out = (float*)d_out;                 // [probs 2044][h 131072]

    k_adj<<<4096, 256, 0, stream>>>(em, adj, blockCnt);
    k_bfs<<<2048, 64, 0, stream>>>(adj, spd);
    k_scan<<<1, 1024, 0, stream>>>(blockCnt, blockOff, counter);
    k_scatter<<<4096, 256, 0, stream>>>(em, blockOff, elist);
    k_edge_bias<<<dim3(256, 3), 256, 0, stream>>>(ef, counter, elist, epw, epb,
                                                  eb1w, eb1b, eblng, eblnb, eb2w, eb2b, vals);
    k_node_proj<<<512, 256, 0, stream>>>(nf, npw, npb, hbuf);

    for (int l = 0; l < LL; l++) {
        k_qkvT<<<128, 256, 0, stream>>>(hbuf, wq + l * 4096, wk + l * 4096, wv + l * 4096,
                                        Qb, KTb, VTb);
        k_attn3<<<dim3(16, 32), 256, 0, stream>>>(Qb, KTb, VTb, spd, elist, blockOff, vals,
                                                  s1wv, s1bv, s2wv, s2bv, nm, l, attO);
        k_oproj_ln1<<<512, 256, 0, stream>>>(attO, wow + l * 4096, wob + l * 64,
                                             ln1g + l * 64, ln1b + l * 64, hbuf);
        k_ffn<<<128, 256, 0, stream>>>(f1w + l * 16384, f1b + l * 256,
                                       f2w + l * 16384, f2b + l * 64,
                                       ln2g + l * 64, ln2b + l * 64, hbuf);
    }

    k_score<<<511, 256, 0, stream>>>(hbuf, sc1w, sc1b, sclng, sclnb, sc2w, sc2b, logits);
    k_copy_h<<<128, 256, 0, stream>>>((const float4*)hbuf, (float4*)(out + 2044));
    k_probs<<<4, 512, 0, stream>>>(logits, nm, out);
}